// Round 5
// baseline (13603.687 us; speedup 1.0000x reference)
//
#include <hip/hip_runtime.h>
#include <hip/hip_bf16.h>

#define E_ 768
#define E2_ 1536
#define E3_ 2304
#define U_ 256
#define NORM_ 27.712812921102035f

typedef unsigned int u32;
typedef unsigned long long u64;

// ---------------- static device workspace ----------------
__device__ __align__(16) float g_Q[U_ * E_];       // D @ Wq + bq
__device__ __align__(16) float g_WQg[U_ * E2_];    // (Wk @ q_t)/norm, row t
__device__ __align__(16) float g_WKVT[E_ * E2_];   // (Wk@Wv)^T : [e][k]
__device__ __align__(16) float g_vb[E_];           // bk@Wv + bv

// exchange payloads (agent-scope atomics, LLC-coherent; no tags — barrier-released)
__device__ __align__(16) float g_bg[E2_];          // gh^t  (buf row t)
__device__ __align__(16) float g_sov[E2_];         // speaker output t
__device__ __align__(16) float g_hst[2 * 8 * E2_]; // hstate[occ-parity][speaker]
__device__ __align__(16) float g_scp[2 * U_];      // scores, parity by target step
// barrier state: 16 padded arrival counters + 16 replicated epoch words
__device__ __align__(128) int g_cnt[16 * 32];
__device__ __align__(128) int g_ep[16 * 32];

__device__ __forceinline__ float bflo(u32 v){ return __uint_as_float(v << 16); }
__device__ __forceinline__ float bfhi(u32 v){ return __uint_as_float(v & 0xffff0000u); }

__device__ __forceinline__ u32 packbf(float lo, float hi){
  u32 a = __float_as_uint(lo), b = __float_as_uint(hi);
  a = (a + 0x7FFFu + ((a >> 16) & 1u)) >> 16;
  b = (b + 0x7FFFu + ((b >> 16) & 1u)) & 0xFFFF0000u;
  return (a & 0xFFFFu) | b;
}
__device__ __forceinline__ unsigned short bfr(float x){
  u32 a = __float_as_uint(x);
  return (unsigned short)((a + 0x7FFFu + ((a >> 16) & 1u)) >> 16);
}

__device__ __forceinline__ float af_ld(const float* p){
  return __hip_atomic_load(p, __ATOMIC_RELAXED, __HIP_MEMORY_SCOPE_AGENT);
}
__device__ __forceinline__ void af_st(float* p, float v){
  __hip_atomic_store(p, v, __ATOMIC_RELAXED, __HIP_MEMORY_SCOPE_AGENT);
}
__device__ __forceinline__ float2 af_ld2(const float* p){
  u64 v = __hip_atomic_load((const u64*)p, __ATOMIC_RELAXED, __HIP_MEMORY_SCOPE_AGENT);
  float2 r;
  r.x = __uint_as_float((u32)v);
  r.y = __uint_as_float((u32)(v >> 32));
  return r;
}

// LDS-only barrier (no vmcnt drain)
__device__ __forceinline__ void bar_lds(){
  asm volatile("s_waitcnt lgkmcnt(0)\n\ts_barrier" ::: "memory");
}

// fence-free grid barrier: arrive (after full __syncthreads vmcnt drain -> payloads
// at LLC) then wait (root sums 16 counters, broadcasts epoch to 16 replicas)
__device__ __forceinline__ void block_arrive(){
  __syncthreads();   // drains each wave's vmcnt => payload stores complete
  if (threadIdx.x == 0) {
    asm volatile("s_waitcnt vmcnt(0)" ::: "memory");   // belt & suspenders (wave 0 holds all pubs)
    __hip_atomic_fetch_add(&g_cnt[(blockIdx.x & 15) * 32], 1,
                           __ATOMIC_RELAXED, __HIP_MEMORY_SCOPE_AGENT);
  }
}
__device__ __forceinline__ void block_wait(int target){
  if (threadIdx.x == 0) {
    if (blockIdx.x == 0) {
      int need = 256 * target;
      for (;;) {
        int sum = 0;
#pragma unroll
        for (int i = 0; i < 16; ++i)
          sum += __hip_atomic_load(&g_cnt[i * 32], __ATOMIC_RELAXED, __HIP_MEMORY_SCOPE_AGENT);
        if (sum >= need) break;
      }
#pragma unroll
      for (int i = 0; i < 16; ++i)
        __hip_atomic_store(&g_ep[i * 32], target, __ATOMIC_RELAXED, __HIP_MEMORY_SCOPE_AGENT);
    } else {
      while (__hip_atomic_load(&g_ep[(blockIdx.x & 15) * 32], __ATOMIC_RELAXED,
                               __HIP_MEMORY_SCOPE_AGENT) < target)
        __builtin_amdgcn_s_sleep(1);
    }
  }
  __syncthreads();
}

__device__ __forceinline__ float wsum(float v){
#pragma unroll
  for (int o = 32; o > 0; o >>= 1) v += __shfl_xor(v, o, 64);
  return v;
}
__device__ __forceinline__ float wmax(float v){
#pragma unroll
  for (int o = 32; o > 0; o >>= 1) v = fmaxf(v, __shfl_xor(v, o, 64));
  return v;
}

// ---------------- init: barrier words + vb ----------------
__global__ __launch_bounds__(256) void init_kernel(const float* bk, const float* Wv,
                                                   const float* bv)
{
  __shared__ float acc4[4][64];
  int tid = threadIdx.x;
  if (blockIdx.x == 0) {
    g_cnt[tid] = 0; g_cnt[tid + 256] = 0;
    g_ep[tid] = 0;  g_ep[tid + 256] = 0;
  }
  int b = blockIdx.x;               // 0..11
  int o = b * 64 + (tid & 63);
  int w = tid >> 6;
  float s = 0.f;
  for (int i2 = w * 192; i2 < w * 192 + 192; ++i2)
    s = fmaf(bk[i2], Wv[(size_t)i2 * E_ + o], s);
  acc4[w][tid & 63] = s;
  __syncthreads();
  if (w == 0)
    g_vb[o] = acc4[0][tid & 63] + acc4[1][tid & 63] + acc4[2][tid & 63] + acc4[3][tid & 63] + bv[o];
}

// ---------------- fp32 tiled GEMM: C = scale*(A@B) + bias ----------------
template<int ASRC, int BNK, int DST, int TC>
__global__ __launch_bounds__(256) void gemm32(const float* __restrict__ Aext, int lda,
                                              const float* __restrict__ B, int ldb,
                                              const float* __restrict__ bias, float scale,
                                              int ldc, int M, int N, int K)
{
  const float* A = (ASRC == 1) ? g_Q : Aext;
  float* C = (DST == 0) ? g_Q : (DST == 1) ? g_WQg : g_WKVT;
  __shared__ float As[64][17];
  __shared__ float Bs[16][65];
  int tid = threadIdx.x;
  int tx = tid & 15, ty = tid >> 4;
  int m0 = blockIdx.y * 64, n0 = blockIdx.x * 64;
  float acc[4][4] = {{0.f}};
  for (int k0 = 0; k0 < K; k0 += 16) {
#pragma unroll
    for (int i = 0; i < 4; ++i) {
      int li = tid + 256 * i;
      int m = li >> 4, kk = li & 15;
      As[m][kk] = A[(size_t)(m0 + m) * lda + k0 + kk];
    }
#pragma unroll
    for (int i = 0; i < 4; ++i) {
      int li = tid + 256 * i;
      if (BNK) {
        int n = li >> 4, kk = li & 15;
        Bs[kk][n] = B[(size_t)(n0 + n) * ldb + k0 + kk];
      } else {
        int kk = li >> 6, n = li & 63;
        Bs[kk][n] = B[(size_t)(k0 + kk) * ldb + n0 + n];
      }
    }
    __syncthreads();
#pragma unroll
    for (int kk = 0; kk < 16; ++kk) {
      float av[4], bv4[4];
#pragma unroll
      for (int i = 0; i < 4; ++i) av[i] = As[ty * 4 + i][kk];
#pragma unroll
      for (int j = 0; j < 4; ++j) bv4[j] = Bs[kk][tx * 4 + j];
#pragma unroll
      for (int i = 0; i < 4; ++i)
#pragma unroll
        for (int j = 0; j < 4; ++j) acc[i][j] = fmaf(av[i], bv4[j], acc[i][j]);
    }
    __syncthreads();
  }
#pragma unroll
  for (int i = 0; i < 4; ++i)
#pragma unroll
    for (int j = 0; j < 4; ++j) {
      int m = m0 + ty * 4 + i, n = n0 + tx * 4 + j;
      float c = acc[i][j] * scale;
      if (bias) c += bias[n];
      if (TC) C[(size_t)n * ldc + m] = c;
      else    C[(size_t)m * ldc + n] = c;
    }
}

// ---------------- persistent sequential kernel ----------------
struct SeqArgs {
  const float *dialogue, *sWih_f, *sWih_b, *sWhh_f, *sWhh_b,
      *sbih_f, *sbih_b, *sbhh_f, *sbhh_b,
      *gWih_f, *gWih_b, *gWhh_f, *gWhh_b, *gbih_f, *gbih_b, *gbhh_f, *gbhh_b,
      *att0, *h0g, *h0s;
  const int* speakers;
  float* out;   // fp32: [U*2E buf][U*2E so]
};

__global__ __launch_bounds__(256, 1) void seq_kernel(SeqArgs a)
{
  const int tid = threadIdx.x, wg = blockIdx.x;
  const int wave = tid >> 6, lane = tid & 63;
  const int h0 = wg * 3;

  __shared__ float wsa[18][768];      // setup: wSA rows fp32 -> then wsakv bf16
  __shared__ float M_l[18][U_];       // M[row][j] = wSA_row . v_j
  __shared__ float ghrow[E2_];        // gh^{t-1}
  __shared__ float bufc[E2_];         // own buf row (row wg)
  __shared__ float hv[E2_];           // hstate[sp] fwd/bwd
  __shared__ float so_f[E2_];         // gathered speaker output
  __shared__ float V_lds[U_][3];      // own att dims of v_j history
  __shared__ float e_lds[U_];
  __shared__ float ghs_s[18], ghg_s[18], sxu[18], gxs[18], mcol[18];
  __shared__ float gxu2[2][18];       // global-GRU u-proj, parity double-buffer
  __shared__ float Mvb_l[18], A0_l[18];
  __shared__ float red4[4], red4b[4], red4c[4], pmax[4], pnum[4][4], att_s[3];
  __shared__ int spk_l[U_], locc_l[U_], pocc_l[U_];

  // ---- stage wSA rows (fp32) + speakers ----
  for (int idx = tid; idx < 18 * 768; idx += 256) {
    int r = idx / 768, e = idx - r * 768;
    int dir = r / 9, lr = r - dir * 9, g = lr / 3, d = lr - g * 3;
    int gr = g * E_ + h0 + d;
    const float* pa = (dir ? a.sWih_b : a.sWih_f) + (size_t)gr * E2_;
    wsa[r][e] = pa[e];
  }
  spk_l[tid] = a.speakers[tid] & 7;
  __syncthreads();
  {
    int mysp = spk_l[tid], lo = -1, cnt = 0;
    for (int s2 = 0; s2 <= tid; ++s2)
      if (spk_l[s2] == mysp) { cnt++; if (s2 < tid) lo = s2; }
    locc_l[tid] = lo;
    pocc_l[tid] = cnt & 1;
  }
  // ---- Mvb = wSA_row . vb ; A0 = wSA_row . att0 (fp32) ----
#pragma unroll
  for (int q = 0; q < 5; ++q) {
    int sr = wave + 4 * q;
    if (sr < 18) {
      float s0 = 0.f, s1 = 0.f;
#pragma unroll
      for (int pp = 0; pp < 12; ++pp) {
        int e = lane + 64 * pp;
        float w = wsa[sr][e];
        s0 = fmaf(w, g_vb[e], s0);
        s1 = fmaf(w, a.att0[e], s1);
      }
      s0 = wsum(s0); s1 = wsum(s1);
      if (lane == 0) { Mvb_l[sr] = s0; A0_l[sr] = s1; }
    }
  }
  // ---- wsakv[r][k] = sum_e wSA_row[e] * WKVT[e][k]  (18 x 1536) ----
  {
    float acc[18][6];
#pragma unroll
    for (int r = 0; r < 18; ++r)
#pragma unroll
      for (int c = 0; c < 6; ++c) acc[r][c] = 0.f;
    for (int e = 0; e < 768; e += 2) {
      const float* B0 = g_WKVT + (size_t)e * E2_ + tid;
      const float* B1 = B0 + E2_;
      float b0[6], b1[6];
#pragma unroll
      for (int c = 0; c < 6; ++c) { b0[c] = B0[256 * c]; b1[c] = B1[256 * c]; }
#pragma unroll
      for (int r = 0; r < 18; ++r) {
        float2 w = ((const float2*)wsa[r])[e >> 1];
#pragma unroll
        for (int c = 0; c < 6; ++c)
          acc[r][c] = fmaf(w.x, b0[c], fmaf(w.y, b1[c], acc[r][c]));
      }
    }
    __syncthreads();
    unsigned short* wsp = (unsigned short*)wsa;
#pragma unroll
    for (int r = 0; r < 18; ++r)
#pragma unroll
      for (int c = 0; c < 6; ++c)
        wsp[r * 1536 + tid + 256 * c] = bfr(acc[r][c]);
  }
  __syncthreads();
  // load wsakv to packed-bf16 registers (same slot layout as wGSO)
  u32 wKV2[5][12];
#pragma unroll
  for (int q = 0; q < 5; ++q) {
    int sr = wave + 4 * q;
    if (sr < 18) {
      const u32* row = (const u32*)wsa + (size_t)sr * 768;
#pragma unroll
      for (int pp = 0; pp < 12; ++pp) wKV2[q][pp] = row[lane + 64 * pp];
    }
  }
  // ---- other weight slices: fp32 -> packed bf16 registers ----
  u32 wSU[5][6], wSHH[5][6], wGHH[5][6], wGSO[5][12], wGU[5][6];
  float bSH[5], bGH[5], bSI[5], bGI[5];
#pragma unroll
  for (int q = 0; q < 5; ++q) {
    int sr = wave + 4 * q;
    if (sr < 18) {
      int dir = sr / 9, lr = sr - dir * 9, g = lr / 3, d = lr - g * 3;
      int gr = g * E_ + h0 + d;
      const float* pa  = (dir ? a.sWih_b : a.sWih_f) + (size_t)gr * E2_;
      const float* ph  = (dir ? a.sWhh_b : a.sWhh_f) + (size_t)gr * E_;
      const float* pgs = (dir ? a.gWih_b : a.gWih_f) + (size_t)gr * E3_;
      const float* pgh = (dir ? a.gWhh_b : a.gWhh_f) + (size_t)gr * E_;
#pragma unroll
      for (int pp = 0; pp < 6; ++pp) {
        int j2 = 2 * (lane + 64 * pp);
        wSU[q][pp]  = packbf(pa[768 + j2], pa[768 + j2 + 1]);
        wSHH[q][pp] = packbf(ph[j2], ph[j2 + 1]);
        wGHH[q][pp] = packbf(pgh[j2], pgh[j2 + 1]);
        wGU[q][pp]  = packbf(pgs[1536 + j2], pgs[1536 + j2 + 1]);
      }
#pragma unroll
      for (int pp = 0; pp < 12; ++pp) {
        int j2 = 2 * (lane + 64 * pp);
        wGSO[q][pp] = packbf(pgs[j2], pgs[j2 + 1]);
      }
      bSH[q] = (dir ? a.sbhh_b : a.sbhh_f)[gr];
      bSI[q] = (dir ? a.sbih_b : a.sbih_f)[gr];
      bGH[q] = (dir ? a.gbhh_b : a.gbhh_f)[gr];
      bGI[q] = (dir ? a.gbih_b : a.gbih_f)[gr];
    }
  }
  // wKV: own 3 rows of WKVT (fp32) for V_lds own dims
  float wKV[24];
  if (wave < 3) {
    const float* kv = g_WKVT + (size_t)(h0 + wave) * E2_;
#pragma unroll
    for (int pp = 0; pp < 12; ++pp) {
      int j2 = 2 * (lane + 64 * pp);
      wKV[2 * pp] = kv[j2]; wKV[2 * pp + 1] = kv[j2 + 1];
    }
  }
  const float vb0 = g_vb[h0], vb1 = g_vb[h0 + 1], vb2 = g_vb[h0 + 2];

  // ---- region A for t = 0: u-only matvecs ----
  {
    const float2* uv = (const float2*)a.dialogue;
#pragma unroll
    for (int q = 0; q < 5; ++q) {
      int sr = wave + 4 * q;
      if (sr < 18) {
        float s3 = 0.f, s4 = 0.f;
#pragma unroll
        for (int pp = 0; pp < 6; ++pp) {
          int j = lane + 64 * pp;
          u32 v3 = wSU[q][pp], v4 = wGU[q][pp];
          float2 xu = uv[j];
          s3 = fmaf(bflo(v3), xu.x, s3); s3 = fmaf(bfhi(v3), xu.y, s3);
          s4 = fmaf(bflo(v4), xu.x, s4); s4 = fmaf(bfhi(v4), xu.y, s4);
        }
        s3 = wsum(s3); s4 = wsum(s4);
        if (lane == 0) { sxu[sr] = s3 + bSI[q]; gxu2[0][sr] = s4 + bGI[q]; }
      }
    }
  }

  for (int t = 0; t < U_; ++t) {
    const int sp = spk_l[t];
    const int locc = locc_l[t];

    // ---- wait alpha(t); publish shadow-computed ahead scores (target t+1) ----
    if (t > 0) {
      block_wait(2 * t);
      if (tid == 0 && wg <= t - 2 && t + 1 < U_)
        af_st(&g_scp[((t + 1) & 1) * U_ + wg],
              red4b[0] + red4b[1] + red4b[2] + red4b[3]);
    }

    // ---- gather gh^{t-1} (+ own-row keep, local + fresh-ahead score partials) ----
    float slp = 0.f, sap = 0.f;
    if (t == 0) {
      for (int i = tid; i < E2_; i += 256) ghrow[i] = a.h0g[i];
    } else {
      const float2* wqt = (const float2*)(g_WQg + (size_t)t * E2_);
      const float2* wqn = (const float2*)(g_WQg + (size_t)((t + 1 < U_) ? t + 1 : t) * E2_);
      const bool own = (wg == t - 1);
      const bool fresh = own && (t + 1 < U_);
#pragma unroll
      for (int c = 0; c < 3; ++c) {
        int i = tid + 256 * c;
        float2 x = af_ld2(&g_bg[2 * i]);
        ghrow[2 * i] = x.x; ghrow[2 * i + 1] = x.y;
        if (own) { bufc[2 * i] = x.x; bufc[2 * i + 1] = x.y; }
        float2 w = wqt[i];
        slp = fmaf(x.x, w.x, slp); slp = fmaf(x.y, w.y, slp);
        if (fresh) {
          float2 wn = wqn[i];
          sap = fmaf(x.x, wn.x, sap); sap = fmaf(x.y, wn.y, sap);
        }
      }
    }
    // ---- gather hstate[sp] (version locc, occ-parity slot) ----
    if (locc >= 0) {
      const float* hb = g_hst + (size_t)((pocc_l[t] ^ 1) * 8 + sp) * E2_;
#pragma unroll
      for (int c = 0; c < 3; ++c) {
        int i = tid + 256 * c;
        float2 x = af_ld2(hb + 2 * i);
        hv[2 * i] = x.x; hv[2 * i + 1] = x.y;
      }
    } else {
#pragma unroll
      for (int c = 0; c < 3; ++c) {
        int i = tid + 256 * c;
        hv[2 * i] = a.h0s[2 * i]; hv[2 * i + 1] = a.h0s[2 * i + 1];
      }
    }
    slp = wsum(slp); sap = wsum(sap);
    if (lane == 0) { red4[wave] = slp; red4c[wave] = sap; }
    bar_lds();

    // ---- publish fresh ahead score (row t-1 for target t+1) ----
    if (t >= 1 && wg == t - 1 && t + 1 < U_ && tid == 0)
      af_st(&g_scp[((t + 1) & 1) * U_ + wg],
            red4c[0] + red4c[1] + red4c[2] + red4c[3]);
    // ---- matvec phase: SHH.hv, GHH.gh, wsakv.gh (M column), V own dims ----
#pragma unroll
    for (int q = 0; q < 5; ++q) {
      int sr = wave + 4 * q;
      if (sr < 18) {
        int dir = sr / 9;
        const float2* hv2 = (const float2*)hv + dir * 384;
        const float2* gv2 = (const float2*)ghrow + dir * 384;
        const float2* gf  = (const float2*)ghrow;
        float s1 = 0.f, s2 = 0.f, sm = 0.f;
#pragma unroll
        for (int pp = 0; pp < 6; ++pp) {
          int j = lane + 64 * pp;
          u32 v1 = wSHH[q][pp], v2 = wGHH[q][pp];
          float2 xh = hv2[j];
          float2 xg = gv2[j];
          s1 = fmaf(bflo(v1), xh.x, s1); s1 = fmaf(bfhi(v1), xh.y, s1);
          s2 = fmaf(bflo(v2), xg.x, s2); s2 = fmaf(bfhi(v2), xg.y, s2);
        }
#pragma unroll
        for (int pp = 0; pp < 12; ++pp) {
          int j = lane + 64 * pp;
          u32 v = wKV2[q][pp];
          float2 x = gf[j];
          sm = fmaf(bflo(v), x.x, sm); sm = fmaf(bfhi(v), x.y, sm);
        }
        s1 = wsum(s1); s2 = wsum(s2); sm = wsum(sm);
        if (lane == 0) {
          ghs_s[sr] = s1 + bSH[q];
          ghg_s[sr] = s2 + bGH[q];
          mcol[sr]  = sm + Mvb_l[sr];
        }
      }
    }
    if (t >= 1 && wave < 3) {
      const float2* gr2 = (const float2*)ghrow;
      float s = 0.f;
#pragma unroll
      for (int pp = 0; pp < 12; ++pp) {
        int j = lane + 64 * pp;
        float2 x = gr2[j];
        s = fmaf(wKV[2 * pp], x.x, s);
        s = fmaf(wKV[2 * pp + 1], x.y, s);
      }
      s = wsum(s);
      if (lane == 0)
        V_lds[t - 1][wave] = s + (wave == 0 ? vb0 : (wave == 1 ? vb1 : vb2));
    }
    bar_lds();

    // ---- softmax + att-input via M (all local data) ----
    if (t == 0) {
      if (tid < 18) gxs[tid] = A0_l[tid];
      if (tid < 3) att_s[tid] = a.att0[h0 + tid];
      bar_lds();
    } else {
      float sc;
      if (tid <= t - 2)      sc = af_ld(&g_scp[(t & 1) * U_ + tid]);
      else if (tid == t - 1) sc = red4[0] + red4[1] + red4[2] + red4[3];
      else                   sc = (tid == t) ? 0.f : -3.0e38f;
      float m = wmax(sc);
      if (lane == 0) pmax[wave] = m;
      bar_lds();
      float mall = fmaxf(fmaxf(pmax[0], pmax[1]), fmaxf(pmax[2], pmax[3]));
      float e = 0.f, n0 = 0.f, n1 = 0.f, n2 = 0.f;
      if (tid <= t) {
        e = expf(sc - mall);
        if (tid < t) { n0 = e * V_lds[tid][0]; n1 = e * V_lds[tid][1]; n2 = e * V_lds[tid][2]; }
        else         { n0 = e * vb0; n1 = e * vb1; n2 = e * vb2; }
      }
      e_lds[tid] = e;
      float es = wsum(e); n0 = wsum(n0); n1 = wsum(n1); n2 = wsum(n2);
      if (lane == 0) { pnum[wave][0] = es; pnum[wave][1] = n0; pnum[wave][2] = n1; pnum[wave][3] = n2; }
      bar_lds();
      float den = pnum[0][0] + pnum[1][0] + pnum[2][0] + pnum[3][0];
      if (tid < 3) {
        float nn = pnum[0][tid + 1] + pnum[1][tid + 1] + pnum[2][tid + 1] + pnum[3][tid + 1];
        att_s[tid] = nn / den;
      }
#pragma unroll
      for (int q = 0; q < 5; ++q) {
        int sr = wave + 4 * q;
        if (sr < 18) {
          float dm = 0.f;
#pragma unroll
          for (int pp = 0; pp < 4; ++pp) {
            int j = lane + 64 * pp;
            dm += (j <= t - 2) ? e_lds[j] * M_l[sr][j] : 0.f;
          }
          dm = wsum(dm);
          if (lane == 0) {
            float mc = mcol[sr];
            gxs[sr] = (dm + e_lds[t - 1] * mc + e_lds[t] * Mvb_l[sr]) / den;
            M_l[sr][t - 1] = mc;
          }
        }
      }
      bar_lds();
    }

    // ---- P2: speaker GRU + publish h / so ----
    if (tid < 6) {
      int dir = tid / 3, d = tid - dir * 3, h = h0 + d;
      float xr = gxs[dir * 9 + d]     + sxu[dir * 9 + d];
      float xz = gxs[dir * 9 + 3 + d] + sxu[dir * 9 + 3 + d];
      float xn = gxs[dir * 9 + 6 + d] + sxu[dir * 9 + 6 + d];
      float hr = ghs_s[dir * 9 + d], hz = ghs_s[dir * 9 + 3 + d], hn = ghs_s[dir * 9 + 6 + d];
      float hp = hv[dir * E_ + h];
      float r = 1.f / (1.f + expf(-(xr + hr)));
      float z = 1.f / (1.f + expf(-(xz + hz)));
      float n = tanhf(xn + r * hn);
      float hnew = (1.f - z) * n + z * hp;
      float resid = dir ? a.dialogue[(size_t)t * E_ + h] : att_s[d];
      float so = hnew + resid;
      af_st(&g_hst[(size_t)(pocc_l[t] * 8 + sp) * E2_ + dir * E_ + h], hnew);
      af_st(&g_sov[dir * E_ + h], so);
      a.out[(size_t)U_ * E2_ + (size_t)t * E2_ + dir * E_ + h] = so;
    }
    block_arrive();   // beta(t) = 2t+1

    // ---- shadow (hidden under beta latency): next-step u matvecs + ahead partials ----
    // NOTE: writes sxu (consumed only by next step's P2) and gxu2[(t+1)&1]
    // (P3 below reads gxu2[t&1]) — no WAR on current step.
    if (t + 1 < U_) {
      const float2* uvn = (const float2*)(a.dialogue + (size_t)(t + 1) * E_);
#pragma unroll
      for (int q = 0; q < 5; ++q) {
        int sr = wave + 4 * q;
        if (sr < 18) {
          float s3 = 0.f, s4 = 0.f;
#pragma unroll
          for (int pp = 0; pp < 6; ++pp) {
            int j = lane + 64 * pp;
            u32 v3 = wSU[q][pp], v4 = wGU[q][pp];
            float2 xu = uvn[j];
            s3 = fmaf(bflo(v3), xu.x, s3); s3 = fmaf(bfhi(v3), xu.y, s3);
            s4 = fmaf(bflo(v4), xu.x, s4); s4 = fmaf(bfhi(v4), xu.y, s4);
          }
          s3 = wsum(s3); s4 = wsum(s4);
          if (lane == 0) { sxu[sr] = s3 + bSI[q]; gxu2[(t + 1) & 1][sr] = s4 + bGI[q]; }
        }
      }
      if (wg <= t - 1 && t + 2 < U_) {
        const float2* bc2 = (const float2*)bufc;
        const float2* wq2 = (const float2*)(g_WQg + (size_t)(t + 2) * E2_);
        float sb = 0.f;
#pragma unroll
        for (int pp = 0; pp < 3; ++pp) {
          int j = tid + 256 * pp;
          float2 x = bc2[j];
          float2 w = wq2[j];
          sb = fmaf(x.x, w.x, sb); sb = fmaf(x.y, w.y, sb);
        }
        sb = wsum(sb);
        if (lane == 0) red4b[wave] = sb;
      }
    }
    block_wait(2 * t + 1);

    // ---- P3: gather so, global GRU, publish gh^t ----
#pragma unroll
    for (int c = 0; c < 3; ++c) {
      int i = tid + 256 * c;
      float2 x = af_ld2(&g_sov[2 * i]);
      so_f[2 * i] = x.x; so_f[2 * i + 1] = x.y;
    }
    bar_lds();
#pragma unroll
    for (int q = 0; q < 5; ++q) {
      int sr = wave + 4 * q;
      if (sr < 18) {
        const float2* so2 = (const float2*)so_f;
        float s = 0.f;
#pragma unroll
        for (int pp = 0; pp < 12; ++pp) {
          int j = lane + 64 * pp;
          u32 v = wGSO[q][pp];
          float2 x = so2[j];
          s = fmaf(bflo(v), x.x, s); s = fmaf(bfhi(v), x.y, s);
        }
        s = wsum(s);
        if (lane == 0) gxs[sr] = s;
      }
    }
    bar_lds();
    if (tid < 6) {
      int dir = tid / 3, d = tid - dir * 3, h = h0 + d;
      float xr = gxs[dir * 9 + d]     + gxu2[t & 1][dir * 9 + d];
      float xz = gxs[dir * 9 + 3 + d] + gxu2[t & 1][dir * 9 + 3 + d];
      float xn = gxs[dir * 9 + 6 + d] + gxu2[t & 1][dir * 9 + 6 + d];
      float hr = ghg_s[dir * 9 + d], hz = ghg_s[dir * 9 + 3 + d], hn = ghg_s[dir * 9 + 6 + d];
      float hp = ghrow[dir * E_ + h];
      float r = 1.f / (1.f + expf(-(xr + hr)));
      float z = 1.f / (1.f + expf(-(xz + hz)));
      float n = tanhf(xn + r * hn);
      float hnew = (1.f - z) * n + z * hp;
      af_st(&g_bg[dir * E_ + h], hnew);
      a.out[(size_t)t * E2_ + dir * E_ + h] = hnew;
    }
    if (t + 1 < U_) block_arrive();   // alpha(t+1) = 2t+2
  }
}

// ---------------- host ----------------
extern "C" void kernel_launch(void* const* d_in, const int* in_sizes, int n_in,
                              void* d_out, int out_size, void* d_ws, size_t ws_size,
                              hipStream_t stream)
{
  (void)in_sizes; (void)n_in; (void)out_size; (void)d_ws; (void)ws_size;
  const float* dialogue = (const float*)d_in[0];
  const int* speakers = (const int*)d_in[1];
  const float* Wq = (const float*)d_in[2];
  const float* bq = (const float*)d_in[3];
  const float* Wk = (const float*)d_in[4];
  const float* bk = (const float*)d_in[5];
  const float* Wv = (const float*)d_in[6];
  const float* bv = (const float*)d_in[7];
  const float* sWih_f = (const float*)d_in[8];
  const float* sWhh_f = (const float*)d_in[9];
  const float* sbih_f = (const float*)d_in[10];
  const float* sbhh_f = (const float*)d_in[11];
  const float* sWih_b = (const float*)d_in[12];
  const float* sWhh_b = (const float*)d_in[13];
  const float* sbih_b = (const float*)d_in[14];
  const float* sbhh_b = (const float*)d_in[15];
  const float* gWih_f = (const float*)d_in[16];
  const float* gWhh_f = (const float*)d_in[17];
  const float* gbih_f = (const float*)d_in[18];
  const float* gbhh_f = (const float*)d_in[19];
  const float* gWih_b = (const float*)d_in[20];
  const float* gWhh_b = (const float*)d_in[21];
  const float* gbih_b = (const float*)d_in[22];
  const float* gbhh_b = (const float*)d_in[23];
  const float* h0_global = (const float*)d_in[24];
  const float* h0_speaker = (const float*)d_in[25];
  const float* att0 = (const float*)d_in[26];

  init_kernel<<<dim3(12), dim3(256), 0, stream>>>(bk, Wv, bv);

  // g_Q = D @ Wq + bq
  gemm32<0, 0, 0, 0><<<dim3(12, 4), dim3(256), 0, stream>>>(
      dialogue, 768, Wq, 768, bq, 1.f, 768, 256, 768, 768);
  // g_WQg = g_Q @ Wk^T / norm
  gemm32<1, 1, 1, 0><<<dim3(24, 4), dim3(256), 0, stream>>>(
      nullptr, 768, Wk, 768, nullptr, 1.f / NORM_, 1536, 256, 1536, 768);
  // g_WKVT[e][k] = (Wk @ Wv)[k][e]
  gemm32<0, 0, 2, 1><<<dim3(12, 24), dim3(256), 0, stream>>>(
      Wk, 768, Wv, 768, nullptr, 1.f, 1536, 1536, 768, 768);

  SeqArgs args;
  args.dialogue = dialogue;
  args.sWih_f = sWih_f; args.sWih_b = sWih_b; args.sWhh_f = sWhh_f; args.sWhh_b = sWhh_b;
  args.sbih_f = sbih_f; args.sbih_b = sbih_b; args.sbhh_f = sbhh_f; args.sbhh_b = sbhh_b;
  args.gWih_f = gWih_f; args.gWih_b = gWih_b; args.gWhh_f = gWhh_f; args.gWhh_b = gWhh_b;
  args.gbih_f = gbih_f; args.gbih_b = gbih_b; args.gbhh_f = gbhh_f; args.gbhh_b = gbhh_b;
  args.att0 = att0; args.h0g = h0_global; args.h0s = h0_speaker;
  args.speakers = speakers;
  args.out = (float*)d_out;

  seq_kernel<<<dim3(256), dim3(256), 0, stream>>>(args);
}

// Round 6
// 12924.750 us; speedup vs baseline: 1.0525x; 1.0525x over previous
//
#include <hip/hip_runtime.h>
#include <hip/hip_bf16.h>

#define E_ 768
#define E2_ 1536
#define E3_ 2304
#define U_ 256
#define NORM_ 27.712812921102035f
#define NREP 4

typedef unsigned int u32;
typedef unsigned long long u64;

// ---------------- static device workspace ----------------
__device__ __align__(16) float g_Q[U_ * E_];       // D @ Wq + bq
__device__ __align__(16) float g_WQg[U_ * E2_];    // (Wk @ q_t)/norm, row t
__device__ __align__(16) float g_WKVT[E_ * E2_];   // (Wk@Wv)^T : [e][k]
__device__ __align__(16) float g_vb[E_];           // bk@Wv + bv
__device__ int g_run;                              // run counter (tag base)

// tagged mailboxes: u64 = {tag:32 | fp32:32}; 4 replicas (64 pollers/line)
__device__ __align__(64) u64 g_mb_bg[NREP * U_ * 8];   // gh^t (buf row t), 6 used
__device__ __align__(64) u64 g_mb_so[NREP * U_ * 8];   // speaker output, 6 used
// barrier-ordered plain payloads
__device__ __align__(16) float g_hst[2 * 8 * E2_];     // hstate[occ-parity][speaker]
__device__ __align__(16) float g_scp[2 * U_];          // scores, parity by target
// flat barrier: 4 arrival counters on separate 256B lines
__device__ __align__(256) int g_cnt4[4 * 64];

__device__ __forceinline__ float bflo(u32 v){ return __uint_as_float(v << 16); }
__device__ __forceinline__ float bfhi(u32 v){ return __uint_as_float(v & 0xffff0000u); }

__device__ __forceinline__ u32 packbf(float lo, float hi){
  u32 a = __float_as_uint(lo), b = __float_as_uint(hi);
  a = (a + 0x7FFFu + ((a >> 16) & 1u)) >> 16;
  b = (b + 0x7FFFu + ((b >> 16) & 1u)) & 0xFFFF0000u;
  return (a & 0xFFFFu) | b;
}
__device__ __forceinline__ unsigned short bfr(float x){
  u32 a = __float_as_uint(x);
  return (unsigned short)((a + 0x7FFFu + ((a >> 16) & 1u)) >> 16);
}

__device__ __forceinline__ float af_ld(const float* p){
  return __hip_atomic_load(p, __ATOMIC_RELAXED, __HIP_MEMORY_SCOPE_AGENT);
}
__device__ __forceinline__ void af_st(float* p, float v){
  __hip_atomic_store(p, v, __ATOMIC_RELAXED, __HIP_MEMORY_SCOPE_AGENT);
}
__device__ __forceinline__ float2 af_ld2(const float* p){
  u64 v = __hip_atomic_load((const u64*)p, __ATOMIC_RELAXED, __HIP_MEMORY_SCOPE_AGENT);
  float2 r;
  r.x = __uint_as_float((u32)v);
  r.y = __uint_as_float((u32)(v >> 32));
  return r;
}
__device__ __forceinline__ u64 aload64(const u64* p){
  return __hip_atomic_load(p, __ATOMIC_RELAXED, __HIP_MEMORY_SCOPE_AGENT);
}
__device__ __forceinline__ void astore64(u64* p, u64 v){
  __hip_atomic_store(p, v, __ATOMIC_RELAXED, __HIP_MEMORY_SCOPE_AGENT);
}
__device__ __forceinline__ u64 pk(float f, u32 tag){ return (u64)__float_as_uint(f) | ((u64)tag << 32); }
__device__ __forceinline__ float pf(u64 v){ return __uint_as_float((u32)v); }
__device__ __forceinline__ u32 ptag(u64 v){ return (u32)(v >> 32); }

// LDS-only barrier (no vmcnt drain)
__device__ __forceinline__ void bar_lds(){
  asm volatile("s_waitcnt lgkmcnt(0)\n\ts_barrier" ::: "memory");
}

// flat grid barrier: arrive = counter RMW after full drain; wait = sum-poll
__device__ __forceinline__ void grid_arrive(){
  __syncthreads();   // per-wave vmcnt drain => all payload stores complete
  if (threadIdx.x == 0) {
    asm volatile("s_waitcnt vmcnt(0)" ::: "memory");
    __hip_atomic_fetch_add(&g_cnt4[(blockIdx.x & 3) * 64], 1,
                           __ATOMIC_RELAXED, __HIP_MEMORY_SCOPE_AGENT);
  }
}
__device__ __forceinline__ void grid_wait(int target){
  if (threadIdx.x == 0) {
    const int need = 256 * target;
    for (;;) {
      int s = __hip_atomic_load(&g_cnt4[0],   __ATOMIC_RELAXED, __HIP_MEMORY_SCOPE_AGENT)
            + __hip_atomic_load(&g_cnt4[64],  __ATOMIC_RELAXED, __HIP_MEMORY_SCOPE_AGENT)
            + __hip_atomic_load(&g_cnt4[128], __ATOMIC_RELAXED, __HIP_MEMORY_SCOPE_AGENT)
            + __hip_atomic_load(&g_cnt4[192], __ATOMIC_RELAXED, __HIP_MEMORY_SCOPE_AGENT);
      if (s >= need) break;
      __builtin_amdgcn_s_sleep(4);
    }
  }
  __syncthreads();
}

__device__ __forceinline__ float wsum(float v){
#pragma unroll
  for (int o = 32; o > 0; o >>= 1) v += __shfl_xor(v, o, 64);
  return v;
}
__device__ __forceinline__ float wmax(float v){
#pragma unroll
  for (int o = 32; o > 0; o >>= 1) v = fmaxf(v, __shfl_xor(v, o, 64));
  return v;
}

// ---------------- init: run counter, barrier counters, vb ----------------
__global__ __launch_bounds__(256) void init_kernel(const float* bk, const float* Wv,
                                                   const float* bv)
{
  __shared__ float acc4[4][64];
  int tid = threadIdx.x;
  if (blockIdx.x == 0) {
    if (tid == 0) g_run = g_run + 1;
    g_cnt4[tid] = 0;
  }
  int b = blockIdx.x;               // 0..11
  int o = b * 64 + (tid & 63);
  int w = tid >> 6;
  float s = 0.f;
  for (int i2 = w * 192; i2 < w * 192 + 192; ++i2)
    s = fmaf(bk[i2], Wv[(size_t)i2 * E_ + o], s);
  acc4[w][tid & 63] = s;
  __syncthreads();
  if (w == 0)
    g_vb[o] = acc4[0][tid & 63] + acc4[1][tid & 63] + acc4[2][tid & 63] + acc4[3][tid & 63] + bv[o];
}

// ---------------- fp32 tiled GEMM: C = scale*(A@B) + bias ----------------
template<int ASRC, int BNK, int DST, int TC>
__global__ __launch_bounds__(256) void gemm32(const float* __restrict__ Aext, int lda,
                                              const float* __restrict__ B, int ldb,
                                              const float* __restrict__ bias, float scale,
                                              int ldc, int M, int N, int K)
{
  const float* A = (ASRC == 1) ? g_Q : Aext;
  float* C = (DST == 0) ? g_Q : (DST == 1) ? g_WQg : g_WKVT;
  __shared__ float As[64][17];
  __shared__ float Bs[16][65];
  int tid = threadIdx.x;
  int tx = tid & 15, ty = tid >> 4;
  int m0 = blockIdx.y * 64, n0 = blockIdx.x * 64;
  float acc[4][4] = {{0.f}};
  for (int k0 = 0; k0 < K; k0 += 16) {
#pragma unroll
    for (int i = 0; i < 4; ++i) {
      int li = tid + 256 * i;
      int m = li >> 4, kk = li & 15;
      As[m][kk] = A[(size_t)(m0 + m) * lda + k0 + kk];
    }
#pragma unroll
    for (int i = 0; i < 4; ++i) {
      int li = tid + 256 * i;
      if (BNK) {
        int n = li >> 4, kk = li & 15;
        Bs[kk][n] = B[(size_t)(n0 + n) * ldb + k0 + kk];
      } else {
        int kk = li >> 6, n = li & 63;
        Bs[kk][n] = B[(size_t)(k0 + kk) * ldb + n0 + n];
      }
    }
    __syncthreads();
#pragma unroll
    for (int kk = 0; kk < 16; ++kk) {
      float av[4], bv4[4];
#pragma unroll
      for (int i = 0; i < 4; ++i) av[i] = As[ty * 4 + i][kk];
#pragma unroll
      for (int j = 0; j < 4; ++j) bv4[j] = Bs[kk][tx * 4 + j];
#pragma unroll
      for (int i = 0; i < 4; ++i)
#pragma unroll
        for (int j = 0; j < 4; ++j) acc[i][j] = fmaf(av[i], bv4[j], acc[i][j]);
    }
    __syncthreads();
  }
#pragma unroll
  for (int i = 0; i < 4; ++i)
#pragma unroll
    for (int j = 0; j < 4; ++j) {
      int m = m0 + ty * 4 + i, n = n0 + tx * 4 + j;
      float c = acc[i][j] * scale;
      if (bias) c += bias[n];
      if (TC) C[(size_t)n * ldc + m] = c;
      else    C[(size_t)m * ldc + n] = c;
    }
}

// ---------------- persistent sequential kernel ----------------
struct SeqArgs {
  const float *dialogue, *sWih_f, *sWih_b, *sWhh_f, *sWhh_b,
      *sbih_f, *sbih_b, *sbhh_f, *sbhh_b,
      *gWih_f, *gWih_b, *gWhh_f, *gWhh_b, *gbih_f, *gbih_b, *gbhh_f, *gbhh_b,
      *att0, *h0g, *h0s;
  const int* speakers;
  float* out;   // fp32: [U*2E buf][U*2E so]
};

__global__ __launch_bounds__(256, 1) void seq_kernel(SeqArgs a)
{
  const int tid = threadIdx.x, wg = blockIdx.x;
  const int wave = tid >> 6, lane = tid & 63;
  const int h0 = wg * 3;
  const int myrep = wg & (NREP - 1);

  __shared__ float wsa[18][768];      // setup: wSA rows fp32 -> then wsakv bf16
  __shared__ float M_l[18][U_];       // M[row][j] = wSA_row . v_j
  __shared__ float ghrow[E2_];        // gh^{t-1}
  __shared__ float bufc[E2_];         // own buf row (row wg)
  __shared__ float hv[E2_];           // hstate[sp] fwd/bwd
  __shared__ float so_f[E2_];         // gathered speaker output
  __shared__ float V_lds[U_][3];      // own att dims of v_j history
  __shared__ float e_lds[U_];
  __shared__ float ghs_s[18], ghg_s[18], sxu[18], gxs[18], mcol[18];
  __shared__ float gxu2[2][18];       // global-GRU u-proj, parity double-buffer
  __shared__ float Mvb_l[18], A0_l[18];
  __shared__ float red4[4], red4b[4], red4c[4], pmax[4], pnum[4][4], att_s[3];
  __shared__ float pub12[12], pubbg[6];
  __shared__ int spk_l[U_], locc_l[U_], pocc_l[U_];

  // ---- stage wSA rows (fp32) + speakers ----
  for (int idx = tid; idx < 18 * 768; idx += 256) {
    int r = idx / 768, e = idx - r * 768;
    int dir = r / 9, lr = r - dir * 9, g = lr / 3, d = lr - g * 3;
    int gr = g * E_ + h0 + d;
    const float* pa = (dir ? a.sWih_b : a.sWih_f) + (size_t)gr * E2_;
    wsa[r][e] = pa[e];
  }
  spk_l[tid] = a.speakers[tid] & 7;
  __syncthreads();
  {
    int mysp = spk_l[tid], lo = -1, cnt = 0;
    for (int s2 = 0; s2 <= tid; ++s2)
      if (spk_l[s2] == mysp) { cnt++; if (s2 < tid) lo = s2; }
    locc_l[tid] = lo;
    pocc_l[tid] = cnt & 1;
  }
  // ---- Mvb = wSA_row . vb ; A0 = wSA_row . att0 (fp32) ----
#pragma unroll
  for (int q = 0; q < 5; ++q) {
    int sr = wave + 4 * q;
    if (sr < 18) {
      float s0 = 0.f, s1 = 0.f;
#pragma unroll
      for (int pp = 0; pp < 12; ++pp) {
        int e = lane + 64 * pp;
        float w = wsa[sr][e];
        s0 = fmaf(w, g_vb[e], s0);
        s1 = fmaf(w, a.att0[e], s1);
      }
      s0 = wsum(s0); s1 = wsum(s1);
      if (lane == 0) { Mvb_l[sr] = s0; A0_l[sr] = s1; }
    }
  }
  // ---- wsakv[r][k] = sum_e wSA_row[e] * WKVT[e][k]  (18 x 1536) ----
  {
    float acc[18][6];
#pragma unroll
    for (int r = 0; r < 18; ++r)
#pragma unroll
      for (int c = 0; c < 6; ++c) acc[r][c] = 0.f;
    for (int e = 0; e < 768; e += 2) {
      const float* B0 = g_WKVT + (size_t)e * E2_ + tid;
      const float* B1 = B0 + E2_;
      float b0[6], b1[6];
#pragma unroll
      for (int c = 0; c < 6; ++c) { b0[c] = B0[256 * c]; b1[c] = B1[256 * c]; }
#pragma unroll
      for (int r = 0; r < 18; ++r) {
        float2 w = ((const float2*)wsa[r])[e >> 1];
#pragma unroll
        for (int c = 0; c < 6; ++c)
          acc[r][c] = fmaf(w.x, b0[c], fmaf(w.y, b1[c], acc[r][c]));
      }
    }
    __syncthreads();
    unsigned short* wsp = (unsigned short*)wsa;
#pragma unroll
    for (int r = 0; r < 18; ++r)
#pragma unroll
      for (int c = 0; c < 6; ++c)
        wsp[r * 1536 + tid + 256 * c] = bfr(acc[r][c]);
  }
  __syncthreads();
  // load wsakv to packed-bf16 registers
  u32 wKV2[5][12];
#pragma unroll
  for (int q = 0; q < 5; ++q) {
    int sr = wave + 4 * q;
    if (sr < 18) {
      const u32* row = (const u32*)wsa + (size_t)sr * 768;
#pragma unroll
      for (int pp = 0; pp < 12; ++pp) wKV2[q][pp] = row[lane + 64 * pp];
    }
  }
  // ---- other weight slices: fp32 -> packed bf16 registers ----
  u32 wSU[5][6], wSHH[5][6], wGHH[5][6], wGSO[5][12], wGU[5][6];
  float bSH[5], bGH[5], bSI[5], bGI[5];
#pragma unroll
  for (int q = 0; q < 5; ++q) {
    int sr = wave + 4 * q;
    if (sr < 18) {
      int dir = sr / 9, lr = sr - dir * 9, g = lr / 3, d = lr - g * 3;
      int gr = g * E_ + h0 + d;
      const float* pa  = (dir ? a.sWih_b : a.sWih_f) + (size_t)gr * E2_;
      const float* ph  = (dir ? a.sWhh_b : a.sWhh_f) + (size_t)gr * E_;
      const float* pgs = (dir ? a.gWih_b : a.gWih_f) + (size_t)gr * E3_;
      const float* pgh = (dir ? a.gWhh_b : a.gWhh_f) + (size_t)gr * E_;
#pragma unroll
      for (int pp = 0; pp < 6; ++pp) {
        int j2 = 2 * (lane + 64 * pp);
        wSU[q][pp]  = packbf(pa[768 + j2], pa[768 + j2 + 1]);
        wSHH[q][pp] = packbf(ph[j2], ph[j2 + 1]);
        wGHH[q][pp] = packbf(pgh[j2], pgh[j2 + 1]);
        wGU[q][pp]  = packbf(pgs[1536 + j2], pgs[1536 + j2 + 1]);
      }
#pragma unroll
      for (int pp = 0; pp < 12; ++pp) {
        int j2 = 2 * (lane + 64 * pp);
        wGSO[q][pp] = packbf(pgs[j2], pgs[j2 + 1]);
      }
      bSH[q] = (dir ? a.sbhh_b : a.sbhh_f)[gr];
      bSI[q] = (dir ? a.sbih_b : a.sbih_f)[gr];
      bGH[q] = (dir ? a.gbhh_b : a.gbhh_f)[gr];
      bGI[q] = (dir ? a.gbih_b : a.gbih_f)[gr];
    }
  }
  // wKV: own 3 rows of WKVT (fp32) for V_lds own dims
  float wKV[24];
  if (wave < 3) {
    const float* kv = g_WKVT + (size_t)(h0 + wave) * E2_;
#pragma unroll
    for (int pp = 0; pp < 12; ++pp) {
      int j2 = 2 * (lane + 64 * pp);
      wKV[2 * pp] = kv[j2]; wKV[2 * pp + 1] = kv[j2 + 1];
    }
  }
  const float vb0 = g_vb[h0], vb1 = g_vb[h0 + 1], vb2 = g_vb[h0 + 2];

  // ---- t = 0 u-only matvecs ----
  {
    const float2* uv = (const float2*)a.dialogue;
#pragma unroll
    for (int q = 0; q < 5; ++q) {
      int sr = wave + 4 * q;
      if (sr < 18) {
        float s3 = 0.f, s4 = 0.f;
#pragma unroll
        for (int pp = 0; pp < 6; ++pp) {
          int j = lane + 64 * pp;
          u32 v3 = wSU[q][pp], v4 = wGU[q][pp];
          float2 xu = uv[j];
          s3 = fmaf(bflo(v3), xu.x, s3); s3 = fmaf(bfhi(v3), xu.y, s3);
          s4 = fmaf(bflo(v4), xu.x, s4); s4 = fmaf(bfhi(v4), xu.y, s4);
        }
        s3 = wsum(s3); s4 = wsum(s4);
        if (lane == 0) { sxu[sr] = s3 + bSI[q]; gxu2[0][sr] = s4 + bGI[q]; }
      }
    }
  }

  const u32 rb = ((u32)g_run) << 9;   // unique tag base per run

  for (int t = 0; t < U_; ++t) {
    const int sp = spk_l[t];
    const int locc = locc_l[t];
    const u32 tagT = rb + (u32)t;

    // ---- tagged bg gather (1-hop; no barrier wait needed) ----
    float slp = 0.f, sap = 0.f;
    if (t == 0) {
      for (int i = tid; i < E2_; i += 256) ghrow[i] = a.h0g[i];
    } else {
      const u64* p = &g_mb_bg[((size_t)myrep * U_ + tid) * 8];
      u64 x0 = aload64(p),     x1 = aload64(p + 1), x2 = aload64(p + 2);
      u64 x3 = aload64(p + 3), x4 = aload64(p + 4), x5 = aload64(p + 5);
      const u32 exp = rb + (u32)(t - 1);
      for (;;) {
        bool ok = (ptag(x0) == exp) & (ptag(x1) == exp) & (ptag(x2) == exp) &
                  (ptag(x3) == exp) & (ptag(x4) == exp) & (ptag(x5) == exp);
        if (ok) break;
        __builtin_amdgcn_s_sleep(1);
        if (ptag(x0) != exp) x0 = aload64(p);
        if (ptag(x1) != exp) x1 = aload64(p + 1);
        if (ptag(x2) != exp) x2 = aload64(p + 2);
        if (ptag(x3) != exp) x3 = aload64(p + 3);
        if (ptag(x4) != exp) x4 = aload64(p + 4);
        if (ptag(x5) != exp) x5 = aload64(p + 5);
      }
      float f0 = pf(x0), f1 = pf(x1), f2 = pf(x2);
      float f3 = pf(x3), f4 = pf(x4), f5 = pf(x5);
      ghrow[3 * tid]          = f0;
      ghrow[3 * tid + 1]      = f1;
      ghrow[3 * tid + 2]      = f2;
      ghrow[E_ + 3 * tid]     = f3;
      ghrow[E_ + 3 * tid + 1] = f4;
      ghrow[E_ + 3 * tid + 2] = f5;
      const bool own = (wg == t - 1);
      if (own) {
        bufc[3 * tid]          = f0;
        bufc[3 * tid + 1]      = f1;
        bufc[3 * tid + 2]      = f2;
        bufc[E_ + 3 * tid]     = f3;
        bufc[E_ + 3 * tid + 1] = f4;
        bufc[E_ + 3 * tid + 2] = f5;
      }
      const float* wq = g_WQg + (size_t)t * E2_;
      slp = f0 * wq[3 * tid] + f1 * wq[3 * tid + 1] + f2 * wq[3 * tid + 2]
          + f3 * wq[E_ + 3 * tid] + f4 * wq[E_ + 3 * tid + 1] + f5 * wq[E_ + 3 * tid + 2];
      if (own && t + 1 < U_) {
        const float* wn = g_WQg + (size_t)(t + 1) * E2_;
        sap = f0 * wn[3 * tid] + f1 * wn[3 * tid + 1] + f2 * wn[3 * tid + 2]
            + f3 * wn[E_ + 3 * tid] + f4 * wn[E_ + 3 * tid + 1] + f5 * wn[E_ + 3 * tid + 2];
      }
    }
    slp = wsum(slp); sap = wsum(sap);
    if (lane == 0) { red4[wave] = slp; red4c[wave] = sap; }
    bar_lds();

    // ---- publish fresh ahead score (row t-1 for target t+1; word never reused) ----
    if (t >= 1 && wg == t - 1 && t + 1 < U_ && tid == 0)
      af_st(&g_scp[((t + 1) & 1) * U_ + wg],
            red4c[0] + red4c[1] + red4c[2] + red4c[3]);
    // ---- gh-only matvecs: GHH, wsakv (M column), V own dims ----
#pragma unroll
    for (int q = 0; q < 5; ++q) {
      int sr = wave + 4 * q;
      if (sr < 18) {
        int dir = sr / 9;
        const float2* gv2 = (const float2*)ghrow + dir * 384;
        const float2* gf  = (const float2*)ghrow;
        float s2 = 0.f, sm = 0.f;
#pragma unroll
        for (int pp = 0; pp < 6; ++pp) {
          int j = lane + 64 * pp;
          u32 v2 = wGHH[q][pp];
          float2 xg = gv2[j];
          s2 = fmaf(bflo(v2), xg.x, s2); s2 = fmaf(bfhi(v2), xg.y, s2);
        }
#pragma unroll
        for (int pp = 0; pp < 12; ++pp) {
          int j = lane + 64 * pp;
          u32 v = wKV2[q][pp];
          float2 x = gf[j];
          sm = fmaf(bflo(v), x.x, sm); sm = fmaf(bfhi(v), x.y, sm);
        }
        s2 = wsum(s2); sm = wsum(sm);
        if (lane == 0) {
          ghg_s[sr] = s2 + bGH[q];
          mcol[sr]  = sm + Mvb_l[sr];
        }
      }
    }
    if (t >= 1 && wave < 3) {
      const float2* gr2 = (const float2*)ghrow;
      float s = 0.f;
#pragma unroll
      for (int pp = 0; pp < 12; ++pp) {
        int j = lane + 64 * pp;
        float2 x = gr2[j];
        s = fmaf(wKV[2 * pp], x.x, s);
        s = fmaf(wKV[2 * pp + 1], x.y, s);
      }
      s = wsum(s);
      if (lane == 0)
        V_lds[t - 1][wave] = s + (wave == 0 ? vb0 : (wave == 1 ? vb1 : vb2));
    }

    // ---- single grid barrier wait (orders hstate/scp/sov anti-deps) ----
    if (t > 0) {
      grid_wait(t);
      // shadow-computed ahead scores (target t+1): safe only after all
      // target-(t-1) readers finished, i.e. after wait alpha(t)
      if (tid == 0 && wg <= t - 2 && t + 1 < U_)
        af_st(&g_scp[((t + 1) & 1) * U_ + wg],
              red4b[0] + red4b[1] + red4b[2] + red4b[3]);
    } else {
      __syncthreads();
    }

    // ---- hstate gather (version locc, occ-parity slot; alpha-ordered) ----
    if (locc >= 0) {
      const float* hb = g_hst + (size_t)((pocc_l[t] ^ 1) * 8 + sp) * E2_;
#pragma unroll
      for (int c = 0; c < 3; ++c) {
        int i = tid + 256 * c;
        float2 x = af_ld2(hb + 2 * i);
        hv[2 * i] = x.x; hv[2 * i + 1] = x.y;
      }
    } else {
#pragma unroll
      for (int c = 0; c < 3; ++c) {
        int i = tid + 256 * c;
        hv[2 * i] = a.h0s[2 * i]; hv[2 * i + 1] = a.h0s[2 * i + 1];
      }
    }
    bar_lds();
    // ---- SHH matvec (needs hv) ----
#pragma unroll
    for (int q = 0; q < 5; ++q) {
      int sr = wave + 4 * q;
      if (sr < 18) {
        int dir = sr / 9;
        const float2* hv2 = (const float2*)hv + dir * 384;
        float s1 = 0.f;
#pragma unroll
        for (int pp = 0; pp < 6; ++pp) {
          int j = lane + 64 * pp;
          u32 v1 = wSHH[q][pp];
          float2 xh = hv2[j];
          s1 = fmaf(bflo(v1), xh.x, s1); s1 = fmaf(bfhi(v1), xh.y, s1);
        }
        s1 = wsum(s1);
        if (lane == 0) ghs_s[sr] = s1 + bSH[q];
      }
    }

    // ---- softmax + att-input via M (scp one-shot reads, alpha-ordered) ----
    if (t == 0) {
      if (tid < 18) gxs[tid] = A0_l[tid];
      if (tid < 3) att_s[tid] = a.att0[h0 + tid];
      bar_lds();
    } else {
      float sc;
      if (tid <= t - 2)      sc = af_ld(&g_scp[(t & 1) * U_ + tid]);
      else if (tid == t - 1) sc = red4[0] + red4[1] + red4[2] + red4[3];
      else                   sc = (tid == t) ? 0.f : -3.0e38f;
      float m = wmax(sc);
      if (lane == 0) pmax[wave] = m;
      bar_lds();
      float mall = fmaxf(fmaxf(pmax[0], pmax[1]), fmaxf(pmax[2], pmax[3]));
      float e = 0.f, n0 = 0.f, n1 = 0.f, n2 = 0.f;
      if (tid <= t) {
        e = expf(sc - mall);
        if (tid < t) { n0 = e * V_lds[tid][0]; n1 = e * V_lds[tid][1]; n2 = e * V_lds[tid][2]; }
        else         { n0 = e * vb0; n1 = e * vb1; n2 = e * vb2; }
      }
      e_lds[tid] = e;
      float es = wsum(e); n0 = wsum(n0); n1 = wsum(n1); n2 = wsum(n2);
      if (lane == 0) { pnum[wave][0] = es; pnum[wave][1] = n0; pnum[wave][2] = n1; pnum[wave][3] = n2; }
      bar_lds();
      float den = pnum[0][0] + pnum[1][0] + pnum[2][0] + pnum[3][0];
      if (tid < 3) {
        float nn = pnum[0][tid + 1] + pnum[1][tid + 1] + pnum[2][tid + 1] + pnum[3][tid + 1];
        att_s[tid] = nn / den;
      }
#pragma unroll
      for (int q = 0; q < 5; ++q) {
        int sr = wave + 4 * q;
        if (sr < 18) {
          float dm = 0.f;
#pragma unroll
          for (int pp = 0; pp < 4; ++pp) {
            int j = lane + 64 * pp;
            dm += (j <= t - 2) ? e_lds[j] * M_l[sr][j] : 0.f;
          }
          dm = wsum(dm);
          if (lane == 0) {
            float mc = mcol[sr];
            gxs[sr] = (dm + e_lds[t - 1] * mc + e_lds[t] * Mvb_l[sr]) / den;
            M_l[sr][t - 1] = mc;
          }
        }
      }
      bar_lds();
    }

    // ---- P2: speaker GRU; publish h (plain) + so (tagged) ----
    if (tid < 6) {
      int dir = tid / 3, d = tid - dir * 3, h = h0 + d;
      float xr = gxs[dir * 9 + d]     + sxu[dir * 9 + d];
      float xz = gxs[dir * 9 + 3 + d] + sxu[dir * 9 + 3 + d];
      float xn = gxs[dir * 9 + 6 + d] + sxu[dir * 9 + 6 + d];
      float hr = ghs_s[dir * 9 + d], hz = ghs_s[dir * 9 + 3 + d], hn = ghs_s[dir * 9 + 6 + d];
      float hp = hv[dir * E_ + h];
      float r = 1.f / (1.f + expf(-(xr + hr)));
      float z = 1.f / (1.f + expf(-(xz + hz)));
      float n = tanhf(xn + r * hn);
      float hnew = (1.f - z) * n + z * hp;
      float resid = dir ? a.dialogue[(size_t)t * E_ + h] : att_s[d];
      float so = hnew + resid;
      pub12[tid] = hnew; pub12[6 + tid] = so;
      af_st(&g_hst[(size_t)(pocc_l[t] * 8 + sp) * E2_ + dir * E_ + h], hnew);
      a.out[(size_t)U_ * E2_ + (size_t)t * E2_ + dir * E_ + h] = so;
    }
    bar_lds();    // pub12 ready; also: P2's sxu reads done before shadow overwrite
    if (tid < 24) {
      int rep = tid & 3, val = tid >> 2;
      astore64(&g_mb_so[((size_t)rep * U_ + wg) * 8 + val], pk(pub12[6 + val], tagT));
    }

    // ---- shadow: next-step u matvecs + ahead score (target t+2) ----
    if (t + 1 < U_) {
      const float2* uvn = (const float2*)(a.dialogue + (size_t)(t + 1) * E_);
#pragma unroll
      for (int q = 0; q < 5; ++q) {
        int sr = wave + 4 * q;
        if (sr < 18) {
          float s3 = 0.f, s4 = 0.f;
#pragma unroll
          for (int pp = 0; pp < 6; ++pp) {
            int j = lane + 64 * pp;
            u32 v3 = wSU[q][pp], v4 = wGU[q][pp];
            float2 xu = uvn[j];
            s3 = fmaf(bflo(v3), xu.x, s3); s3 = fmaf(bfhi(v3), xu.y, s3);
            s4 = fmaf(bflo(v4), xu.x, s4); s4 = fmaf(bfhi(v4), xu.y, s4);
          }
          s3 = wsum(s3); s4 = wsum(s4);
          if (lane == 0) { sxu[sr] = s3 + bSI[q]; gxu2[(t + 1) & 1][sr] = s4 + bGI[q]; }
        }
      }
      if (wg <= t - 1 && t + 2 < U_) {
        const float2* bc2 = (const float2*)bufc;
        const float2* wq2 = (const float2*)(g_WQg + (size_t)(t + 2) * E2_);
        float sb = 0.f;
#pragma unroll
        for (int pp = 0; pp < 3; ++pp) {
          int j = tid + 256 * pp;
          float2 x = bc2[j];
          float2 w = wq2[j];
          sb = fmaf(x.x, w.x, sb); sb = fmaf(x.y, w.y, sb);
        }
        sb = wsum(sb);
        if (lane == 0) red4b[wave] = sb;
      }
    }

    // ---- tagged so gather (1-hop) ----
    {
      const u64* p = &g_mb_so[((size_t)myrep * U_ + tid) * 8];
      u64 x0 = aload64(p),     x1 = aload64(p + 1), x2 = aload64(p + 2);
      u64 x3 = aload64(p + 3), x4 = aload64(p + 4), x5 = aload64(p + 5);
      for (;;) {
        bool ok = (ptag(x0) == tagT) & (ptag(x1) == tagT) & (ptag(x2) == tagT) &
                  (ptag(x3) == tagT) & (ptag(x4) == tagT) & (ptag(x5) == tagT);
        if (ok) break;
        __builtin_amdgcn_s_sleep(1);
        if (ptag(x0) != tagT) x0 = aload64(p);
        if (ptag(x1) != tagT) x1 = aload64(p + 1);
        if (ptag(x2) != tagT) x2 = aload64(p + 2);
        if (ptag(x3) != tagT) x3 = aload64(p + 3);
        if (ptag(x4) != tagT) x4 = aload64(p + 4);
        if (ptag(x5) != tagT) x5 = aload64(p + 5);
      }
      so_f[3 * tid]          = pf(x0);
      so_f[3 * tid + 1]      = pf(x1);
      so_f[3 * tid + 2]      = pf(x2);
      so_f[E_ + 3 * tid]     = pf(x3);
      so_f[E_ + 3 * tid + 1] = pf(x4);
      so_f[E_ + 3 * tid + 2] = pf(x5);
    }
    bar_lds();
    // ---- P3: GSO matvec, global GRU, publish bg (tagged) ----
#pragma unroll
    for (int q = 0; q < 5; ++q) {
      int sr = wave + 4 * q;
      if (sr < 18) {
        const float2* so2 = (const float2*)so_f;
        float s = 0.f;
#pragma unroll
        for (int pp = 0; pp < 12; ++pp) {
          int j = lane + 64 * pp;
          u32 v = wGSO[q][pp];
          float2 x = so2[j];
          s = fmaf(bflo(v), x.x, s); s = fmaf(bfhi(v), x.y, s);
        }
        s = wsum(s);
        if (lane == 0) gxs[sr] = s;
      }
    }
    bar_lds();
    if (tid < 6) {
      int dir = tid / 3, d = tid - dir * 3, h = h0 + d;
      float xr = gxs[dir * 9 + d]     + gxu2[t & 1][dir * 9 + d];
      float xz = gxs[dir * 9 + 3 + d] + gxu2[t & 1][dir * 9 + 3 + d];
      float xn = gxs[dir * 9 + 6 + d] + gxu2[t & 1][dir * 9 + 6 + d];
      float hr = ghg_s[dir * 9 + d], hz = ghg_s[dir * 9 + 3 + d], hn = ghg_s[dir * 9 + 6 + d];
      float hp = ghrow[dir * E_ + h];
      float r = 1.f / (1.f + expf(-(xr + hr)));
      float z = 1.f / (1.f + expf(-(xz + hz)));
      float n = tanhf(xn + r * hn);
      float hnew = (1.f - z) * n + z * hp;
      pubbg[tid] = hnew;
      a.out[(size_t)t * E2_ + dir * E_ + h] = hnew;
    }
    bar_lds();
    if (tid < 24) {
      int rep = tid & 3, val = tid >> 2;
      astore64(&g_mb_bg[((size_t)rep * U_ + wg) * 8 + val], pk(pubbg[val], tagT));
    }
    if (t + 1 < U_) grid_arrive();   // alpha(t+1)
  }
}

// ---------------- host ----------------
extern "C" void kernel_launch(void* const* d_in, const int* in_sizes, int n_in,
                              void* d_out, int out_size, void* d_ws, size_t ws_size,
                              hipStream_t stream)
{
  (void)in_sizes; (void)n_in; (void)out_size; (void)d_ws; (void)ws_size;
  const float* dialogue = (const float*)d_in[0];
  const int* speakers = (const int*)d_in[1];
  const float* Wq = (const float*)d_in[2];
  const float* bq = (const float*)d_in[3];
  const float* Wk = (const float*)d_in[4];
  const float* bk = (const float*)d_in[5];
  const float* Wv = (const float*)d_in[6];
  const float* bv = (const float*)d_in[7];
  const float* sWih_f = (const float*)d_in[8];
  const float* sWhh_f = (const float*)d_in[9];
  const float* sbih_f = (const float*)d_in[10];
  const float* sbhh_f = (const float*)d_in[11];
  const float* sWih_b = (const float*)d_in[12];
  const float* sWhh_b = (const float*)d_in[13];
  const float* sbih_b = (const float*)d_in[14];
  const float* sbhh_b = (const float*)d_in[15];
  const float* gWih_f = (const float*)d_in[16];
  const float* gWhh_f = (const float*)d_in[17];
  const float* gbih_f = (const float*)d_in[18];
  const float* gbhh_f = (const float*)d_in[19];
  const float* gWih_b = (const float*)d_in[20];
  const float* gWhh_b = (const float*)d_in[21];
  const float* gbih_b = (const float*)d_in[22];
  const float* gbhh_b = (const float*)d_in[23];
  const float* h0_global = (const float*)d_in[24];
  const float* h0_speaker = (const float*)d_in[25];
  const float* att0 = (const float*)d_in[26];

  init_kernel<<<dim3(12), dim3(256), 0, stream>>>(bk, Wv, bv);

  // g_Q = D @ Wq + bq
  gemm32<0, 0, 0, 0><<<dim3(12, 4), dim3(256), 0, stream>>>(
      dialogue, 768, Wq, 768, bq, 1.f, 768, 256, 768, 768);
  // g_WQg = g_Q @ Wk^T / norm
  gemm32<1, 1, 1, 0><<<dim3(24, 4), dim3(256), 0, stream>>>(
      nullptr, 768, Wk, 768, nullptr, 1.f / NORM_, 1536, 256, 1536, 768);
  // g_WKVT[e][k] = (Wk @ Wv)[k][e]
  gemm32<0, 0, 2, 1><<<dim3(12, 24), dim3(256), 0, stream>>>(
      Wk, 768, Wv, 768, nullptr, 1.f, 1536, 1536, 768, 768);

  SeqArgs args;
  args.dialogue = dialogue;
  args.sWih_f = sWih_f; args.sWih_b = sWih_b; args.sWhh_f = sWhh_f; args.sWhh_b = sWhh_b;
  args.sbih_f = sbih_f; args.sbih_b = sbih_b; args.sbhh_f = sbhh_f; args.sbhh_b = sbhh_b;
  args.gWih_f = gWih_f; args.gWih_b = gWih_b; args.gWhh_f = gWhh_f; args.gWhh_b = gWhh_b;
  args.gbih_f = gbih_f; args.gbih_b = gbih_b; args.gbhh_f = gbhh_f; args.gbhh_b = gbhh_b;
  args.att0 = att0; args.h0g = h0_global; args.h0s = h0_speaker;
  args.speakers = speakers;
  args.out = (float*)d_out;

  seq_kernel<<<dim3(256), dim3(256), 0, stream>>>(args);
}

// Round 7
// 11931.485 us; speedup vs baseline: 1.1402x; 1.0832x over previous
//
#include <hip/hip_runtime.h>
#include <hip/hip_bf16.h>

#define E_ 768
#define E2_ 1536
#define E3_ 2304
#define U_ 256
#define NORM_ 27.712812921102035f
#define NREP 16

typedef unsigned int u32;
typedef unsigned long long u64;

// ---------------- static device workspace ----------------
__device__ __align__(16) float g_Q[U_ * E_];       // D @ Wq + bq
__device__ __align__(16) float g_WQg[U_ * E2_];    // (Wk @ q_t)/norm, row t
__device__ __align__(16) float g_WKVT[E_ * E2_];   // (Wk@Wv)^T : [e][k]
__device__ __align__(16) float g_vb[E_];           // bk@Wv + bv
__device__ int g_run;                              // run counter (tag base)

// tagged mailboxes: u64 = {tag:32 | payload:32}; payload = 2 bf16 (or fp32 score)
// NREP=16 replicas -> ~16 pollers per line (round-3 regime, the fastest measured)
__device__ __align__(64) u64 g_mb_bg[NREP * U_ * 4];          // gh^t row dims (3 slots)
__device__ __align__(64) u64 g_mb_so[NREP * U_ * 4];          // so row dims (3 slots)
__device__ __align__(64) u64 g_mb_h [2 * NREP * U_ * 8 * 4];  // hstate, occ-parity slots
__device__ __align__(64) u64 g_mb_sc[2 * NREP * U_];          // scores, parity by target

__device__ __forceinline__ float bflo(u32 v){ return __uint_as_float(v << 16); }
__device__ __forceinline__ float bfhi(u32 v){ return __uint_as_float(v & 0xffff0000u); }

__device__ __forceinline__ u32 packbf(float lo, float hi){
  u32 a = __float_as_uint(lo), b = __float_as_uint(hi);
  a = (a + 0x7FFFu + ((a >> 16) & 1u)) >> 16;
  b = (b + 0x7FFFu + ((b >> 16) & 1u)) & 0xFFFF0000u;
  return (a & 0xFFFFu) | b;
}
__device__ __forceinline__ unsigned short bfr(float x){
  u32 a = __float_as_uint(x);
  return (unsigned short)((a + 0x7FFFu + ((a >> 16) & 1u)) >> 16);
}

__device__ __forceinline__ u64 aload64(const u64* p){
  return __hip_atomic_load(p, __ATOMIC_RELAXED, __HIP_MEMORY_SCOPE_AGENT);
}
__device__ __forceinline__ void astore64(u64* p, u64 v){
  __hip_atomic_store(p, v, __ATOMIC_RELAXED, __HIP_MEMORY_SCOPE_AGENT);
}
__device__ __forceinline__ u64 pk(float f, u32 tag){ return (u64)__float_as_uint(f) | ((u64)tag << 32); }
__device__ __forceinline__ float pf(u64 v){ return __uint_as_float((u32)v); }
__device__ __forceinline__ u32 ptag(u64 v){ return (u32)(v >> 32); }

// LDS-only barrier (no vmcnt drain; mailboxes are self-validating via tags)
__device__ __forceinline__ void bar_lds(){
  asm volatile("s_waitcnt lgkmcnt(0)\n\ts_barrier" ::: "memory");
}

__device__ __forceinline__ float wsum(float v){
#pragma unroll
  for (int o = 32; o > 0; o >>= 1) v += __shfl_xor(v, o, 64);
  return v;
}
__device__ __forceinline__ float wmax(float v){
#pragma unroll
  for (int o = 32; o > 0; o >>= 1) v = fmaxf(v, __shfl_xor(v, o, 64));
  return v;
}

// ---------------- init: run counter + vb ----------------
__global__ __launch_bounds__(256) void init_kernel(const float* bk, const float* Wv,
                                                   const float* bv)
{
  __shared__ float acc4[4][64];
  int tid = threadIdx.x;
  if (blockIdx.x == 0 && tid == 0) g_run = g_run + 1;
  int b = blockIdx.x;               // 0..11
  int o = b * 64 + (tid & 63);
  int w = tid >> 6;
  float s = 0.f;
  for (int i2 = w * 192; i2 < w * 192 + 192; ++i2)
    s = fmaf(bk[i2], Wv[(size_t)i2 * E_ + o], s);
  acc4[w][tid & 63] = s;
  __syncthreads();
  if (w == 0)
    g_vb[o] = acc4[0][tid & 63] + acc4[1][tid & 63] + acc4[2][tid & 63] + acc4[3][tid & 63] + bv[o];
}

// ---------------- fp32 tiled GEMM: C = scale*(A@B) + bias ----------------
template<int ASRC, int BNK, int DST, int TC>
__global__ __launch_bounds__(256) void gemm32(const float* __restrict__ Aext, int lda,
                                              const float* __restrict__ B, int ldb,
                                              const float* __restrict__ bias, float scale,
                                              int ldc, int M, int N, int K)
{
  const float* A = (ASRC == 1) ? g_Q : Aext;
  float* C = (DST == 0) ? g_Q : (DST == 1) ? g_WQg : g_WKVT;
  __shared__ float As[64][17];
  __shared__ float Bs[16][65];
  int tid = threadIdx.x;
  int tx = tid & 15, ty = tid >> 4;
  int m0 = blockIdx.y * 64, n0 = blockIdx.x * 64;
  float acc[4][4] = {{0.f}};
  for (int k0 = 0; k0 < K; k0 += 16) {
#pragma unroll
    for (int i = 0; i < 4; ++i) {
      int li = tid + 256 * i;
      int m = li >> 4, kk = li & 15;
      As[m][kk] = A[(size_t)(m0 + m) * lda + k0 + kk];
    }
#pragma unroll
    for (int i = 0; i < 4; ++i) {
      int li = tid + 256 * i;
      if (BNK) {
        int n = li >> 4, kk = li & 15;
        Bs[kk][n] = B[(size_t)(n0 + n) * ldb + k0 + kk];
      } else {
        int kk = li >> 6, n = li & 63;
        Bs[kk][n] = B[(size_t)(k0 + kk) * ldb + n0 + n];
      }
    }
    __syncthreads();
#pragma unroll
    for (int kk = 0; kk < 16; ++kk) {
      float av[4], bv4[4];
#pragma unroll
      for (int i = 0; i < 4; ++i) av[i] = As[ty * 4 + i][kk];
#pragma unroll
      for (int j = 0; j < 4; ++j) bv4[j] = Bs[kk][tx * 4 + j];
#pragma unroll
      for (int i = 0; i < 4; ++i)
#pragma unroll
        for (int j = 0; j < 4; ++j) acc[i][j] = fmaf(av[i], bv4[j], acc[i][j]);
    }
    __syncthreads();
  }
#pragma unroll
  for (int i = 0; i < 4; ++i)
#pragma unroll
    for (int j = 0; j < 4; ++j) {
      int m = m0 + ty * 4 + i, n = n0 + tx * 4 + j;
      float c = acc[i][j] * scale;
      if (bias) c += bias[n];
      if (TC) C[(size_t)n * ldc + m] = c;
      else    C[(size_t)m * ldc + n] = c;
    }
}

// ---------------- persistent sequential kernel ----------------
struct SeqArgs {
  const float *dialogue, *sWih_f, *sWih_b, *sWhh_f, *sWhh_b,
      *sbih_f, *sbih_b, *sbhh_f, *sbhh_b,
      *gWih_f, *gWih_b, *gWhh_f, *gWhh_b, *gbih_f, *gbih_b, *gbhh_f, *gbhh_b,
      *att0, *h0g, *h0s;
  const int* speakers;
  float* out;   // fp32: [U*2E buf][U*2E so]
};

__global__ __launch_bounds__(256, 1) void seq_kernel(SeqArgs a)
{
  const int tid = threadIdx.x, wg = blockIdx.x;
  const int wave = tid >> 6, lane = tid & 63;
  const int h0 = wg * 3;
  const int myrep = wg & (NREP - 1);

  __shared__ float wsa[18][768];      // setup: wSA rows fp32 -> then wsakv bf16
  __shared__ float M_l[18][U_];       // M[row][j] = wSA_row . v_j
  __shared__ float ghrow[E2_];        // gh^{t-1} (bf16-transported)
  __shared__ float bufc[E2_];         // own buf row (row wg)
  __shared__ float hv[E2_];           // hstate[sp] fwd/bwd (bf16-transported)
  __shared__ float so_f[E2_];         // gathered speaker output
  __shared__ float V_lds[U_][3];      // own att dims of v_j history
  __shared__ float e_lds[U_];
  __shared__ float ghs_s[18], ghg_s[18], sxu[18], gxu[18], gxs[18], mcol[18];
  __shared__ float Mvb_l[18], A0_l[18];
  __shared__ float red4[4], red4b[4], pmax[4], pnum[4][4], att_s[3];
  __shared__ float pub12[12], pubbg[6];
  __shared__ float hloc[8][6];        // fp32 carry: own hstate dims per speaker
  __shared__ float ghloc[6];          // fp32 carry: own gh dims
  __shared__ int spk_l[U_], locc_l[U_], pocc_l[U_];

  // ---- stage wSA rows (fp32) + speakers ----
  for (int idx = tid; idx < 18 * 768; idx += 256) {
    int r = idx / 768, e = idx - r * 768;
    int dir = r / 9, lr = r - dir * 9, g = lr / 3, d = lr - g * 3;
    int gr = g * E_ + h0 + d;
    const float* pa = (dir ? a.sWih_b : a.sWih_f) + (size_t)gr * E2_;
    wsa[r][e] = pa[e];
  }
  spk_l[tid] = a.speakers[tid] & 7;
  __syncthreads();
  {
    int mysp = spk_l[tid], lo = -1, cnt = 0;
    for (int s2 = 0; s2 <= tid; ++s2)
      if (spk_l[s2] == mysp) { cnt++; if (s2 < tid) lo = s2; }
    locc_l[tid] = lo;
    pocc_l[tid] = cnt & 1;
  }
  // ---- Mvb = wSA_row . vb ; A0 = wSA_row . att0 (fp32) ----
#pragma unroll
  for (int q = 0; q < 5; ++q) {
    int sr = wave + 4 * q;
    if (sr < 18) {
      float s0 = 0.f, s1 = 0.f;
#pragma unroll
      for (int pp = 0; pp < 12; ++pp) {
        int e = lane + 64 * pp;
        float w = wsa[sr][e];
        s0 = fmaf(w, g_vb[e], s0);
        s1 = fmaf(w, a.att0[e], s1);
      }
      s0 = wsum(s0); s1 = wsum(s1);
      if (lane == 0) { Mvb_l[sr] = s0; A0_l[sr] = s1; }
    }
  }
  // ---- wsakv[r][k] = sum_e wSA_row[e] * WKVT[e][k]  (18 x 1536, -> bf16) ----
  {
    float acc[18][6];
#pragma unroll
    for (int r = 0; r < 18; ++r)
#pragma unroll
      for (int c = 0; c < 6; ++c) acc[r][c] = 0.f;
    for (int e = 0; e < 768; e += 2) {
      const float* B0 = g_WKVT + (size_t)e * E2_ + tid;
      const float* B1 = B0 + E2_;
      float b0[6], b1[6];
#pragma unroll
      for (int c = 0; c < 6; ++c) { b0[c] = B0[256 * c]; b1[c] = B1[256 * c]; }
#pragma unroll
      for (int r = 0; r < 18; ++r) {
        float2 w = ((const float2*)wsa[r])[e >> 1];
#pragma unroll
        for (int c = 0; c < 6; ++c)
          acc[r][c] = fmaf(w.x, b0[c], fmaf(w.y, b1[c], acc[r][c]));
      }
    }
    __syncthreads();
    unsigned short* wsp = (unsigned short*)wsa;
#pragma unroll
    for (int r = 0; r < 18; ++r)
#pragma unroll
      for (int c = 0; c < 6; ++c)
        wsp[r * 1536 + tid + 256 * c] = bfr(acc[r][c]);
  }
  __syncthreads();
  // load wsakv to packed-bf16 registers
  u32 wKV2[5][12];
#pragma unroll
  for (int q = 0; q < 5; ++q) {
    int sr = wave + 4 * q;
    if (sr < 18) {
      const u32* row = (const u32*)wsa + (size_t)sr * 768;
#pragma unroll
      for (int pp = 0; pp < 12; ++pp) wKV2[q][pp] = row[lane + 64 * pp];
    }
  }
  // ---- other weight slices: fp32 -> packed bf16 registers ----
  u32 wSU[5][6], wSHH[5][6], wGHH[5][6], wGSO[5][12], wGU[5][6];
  float bSH[5], bGH[5], bSI[5], bGI[5];
#pragma unroll
  for (int q = 0; q < 5; ++q) {
    int sr = wave + 4 * q;
    if (sr < 18) {
      int dir = sr / 9, lr = sr - dir * 9, g = lr / 3, d = lr - g * 3;
      int gr = g * E_ + h0 + d;
      const float* pa  = (dir ? a.sWih_b : a.sWih_f) + (size_t)gr * E2_;
      const float* ph  = (dir ? a.sWhh_b : a.sWhh_f) + (size_t)gr * E_;
      const float* pgs = (dir ? a.gWih_b : a.gWih_f) + (size_t)gr * E3_;
      const float* pgh = (dir ? a.gWhh_b : a.gWhh_f) + (size_t)gr * E_;
#pragma unroll
      for (int pp = 0; pp < 6; ++pp) {
        int j2 = 2 * (lane + 64 * pp);
        wSU[q][pp]  = packbf(pa[768 + j2], pa[768 + j2 + 1]);
        wSHH[q][pp] = packbf(ph[j2], ph[j2 + 1]);
        wGHH[q][pp] = packbf(pgh[j2], pgh[j2 + 1]);
        wGU[q][pp]  = packbf(pgs[1536 + j2], pgs[1536 + j2 + 1]);
      }
#pragma unroll
      for (int pp = 0; pp < 12; ++pp) {
        int j2 = 2 * (lane + 64 * pp);
        wGSO[q][pp] = packbf(pgs[j2], pgs[j2 + 1]);
      }
      bSH[q] = (dir ? a.sbhh_b : a.sbhh_f)[gr];
      bSI[q] = (dir ? a.sbih_b : a.sbih_f)[gr];
      bGH[q] = (dir ? a.gbhh_b : a.gbhh_f)[gr];
      bGI[q] = (dir ? a.gbih_b : a.gbih_f)[gr];
    }
  }
  // wKV: own 3 rows of WKVT (fp32) for V_lds own dims
  float wKV[24];
  if (wave < 3) {
    const float* kv = g_WKVT + (size_t)(h0 + wave) * E2_;
#pragma unroll
    for (int pp = 0; pp < 12; ++pp) {
      int j2 = 2 * (lane + 64 * pp);
      wKV[2 * pp] = kv[j2]; wKV[2 * pp + 1] = kv[j2 + 1];
    }
  }
  const float vb0 = g_vb[h0], vb1 = g_vb[h0 + 1], vb2 = g_vb[h0 + 2];
  // fp32 carry init: own gh dims
  if (tid < 6) ghloc[tid] = a.h0g[(tid / 3) * E_ + h0 + (tid % 3)];
  __syncthreads();

  const u32 rb = ((u32)g_run) << 9;   // unique tag base per run

  for (int t = 0; t < U_; ++t) {
    const int sp = spk_l[t];
    const int locc = locc_l[t];
    const u32 tagT = rb + (u32)t;
    const float2* uv = (const float2*)(a.dialogue + (size_t)t * E_);

    // ---- pre-hop: u matvecs (overlap producer store flight) ----
#pragma unroll
    for (int q = 0; q < 5; ++q) {
      int sr = wave + 4 * q;
      if (sr < 18) {
        float s3 = 0.f, s4 = 0.f;
#pragma unroll
        for (int pp = 0; pp < 6; ++pp) {
          int j = lane + 64 * pp;
          u32 v3 = wSU[q][pp], v4 = wGU[q][pp];
          float2 xu = uv[j];
          s3 = fmaf(bflo(v3), xu.x, s3); s3 = fmaf(bfhi(v3), xu.y, s3);
          s4 = fmaf(bflo(v4), xu.x, s4); s4 = fmaf(bfhi(v4), xu.y, s4);
        }
        s3 = wsum(s3); s4 = wsum(s4);
        if (lane == 0) { sxu[sr] = s3 + bSI[q]; gxu[sr] = s4 + bGI[q]; }
      }
    }

    // ---- bg gather (tag t-1, 3 bf16-pair slots) + local score ----
    float slp = 0.f;
    if (t == 0) {
      for (int i = tid; i < E2_; i += 256) ghrow[i] = a.h0g[i];
    } else {
      const u64* p = &g_mb_bg[((size_t)myrep * U_ + tid) * 4];
      u64 x0 = aload64(p), x1 = aload64(p + 1), x2 = aload64(p + 2);
      const u32 exp = rb + (u32)(t - 1);
      for (;;) {
        bool ok = (ptag(x0) == exp) & (ptag(x1) == exp) & (ptag(x2) == exp);
        if (ok) break;
        if (ptag(x0) != exp) x0 = aload64(p);
        if (ptag(x1) != exp) x1 = aload64(p + 1);
        if (ptag(x2) != exp) x2 = aload64(p + 2);
      }
      u32 w0 = (u32)x0, w1 = (u32)x1, w2 = (u32)x2;
      float f0 = bflo(w0), f1 = bfhi(w0), f2 = bflo(w1);
      float f3 = bfhi(w1), f4 = bflo(w2), f5 = bfhi(w2);
      ghrow[3 * tid]          = f0;
      ghrow[3 * tid + 1]      = f1;
      ghrow[3 * tid + 2]      = f2;
      ghrow[E_ + 3 * tid]     = f3;
      ghrow[E_ + 3 * tid + 1] = f4;
      ghrow[E_ + 3 * tid + 2] = f5;
      if (wg == t - 1) {
        bufc[3 * tid]          = f0;
        bufc[3 * tid + 1]      = f1;
        bufc[3 * tid + 2]      = f2;
        bufc[E_ + 3 * tid]     = f3;
        bufc[E_ + 3 * tid + 1] = f4;
        bufc[E_ + 3 * tid + 2] = f5;
      }
      const float* wq = g_WQg + (size_t)t * E2_;
      slp = f0 * wq[3 * tid] + f1 * wq[3 * tid + 1] + f2 * wq[3 * tid + 2]
          + f3 * wq[E_ + 3 * tid] + f4 * wq[E_ + 3 * tid + 1] + f5 * wq[E_ + 3 * tid + 2];
    }
    // ---- h gather (tag locc, occurrence-parity slot) ----
    if (locc >= 0) {
      const int spar = pocc_l[t] ^ 1;
      const u64* p = &g_mb_h[((((size_t)spar * NREP + myrep) * U_ + tid) * 8 + sp) * 4];
      u64 x0 = aload64(p), x1 = aload64(p + 1), x2 = aload64(p + 2);
      const u32 exp = rb + (u32)locc;
      for (;;) {
        bool ok = (ptag(x0) == exp) & (ptag(x1) == exp) & (ptag(x2) == exp);
        if (ok) break;
        if (ptag(x0) != exp) x0 = aload64(p);
        if (ptag(x1) != exp) x1 = aload64(p + 1);
        if (ptag(x2) != exp) x2 = aload64(p + 2);
      }
      u32 w0 = (u32)x0, w1 = (u32)x1, w2 = (u32)x2;
      hv[3 * tid]          = bflo(w0);
      hv[3 * tid + 1]      = bfhi(w0);
      hv[3 * tid + 2]      = bflo(w1);
      hv[E_ + 3 * tid]     = bfhi(w1);
      hv[E_ + 3 * tid + 1] = bflo(w2);
      hv[E_ + 3 * tid + 2] = bfhi(w2);
    } else {
#pragma unroll
      for (int k = 0; k < 6; ++k) {
        int idx = (k / 3) * E_ + 3 * tid + (k % 3);
        hv[idx] = a.h0s[idx];
      }
    }
    slp = wsum(slp);
    if (lane == 0) red4[wave] = slp;
    bar_lds();

    // ---- ahead score for target t+1 (from bufc; includes row t-1) ----
    if (t >= 1 && wg <= t - 1 && t + 1 < U_) {
      const float2* bc2 = (const float2*)bufc;
      const float2* wq2 = (const float2*)(g_WQg + (size_t)(t + 1) * E2_);
      float sb = 0.f;
#pragma unroll
      for (int pp = 0; pp < 3; ++pp) {
        int j = tid + 256 * pp;
        float2 x = bc2[j];
        float2 w = wq2[j];
        sb = fmaf(x.x, w.x, sb); sb = fmaf(x.y, w.y, sb);
      }
      sb = wsum(sb);
      if (lane == 0) red4b[wave] = sb;
    }
    // ---- matvecs: SHH(hv), GHH(gh), wsakv(gh)->mcol; V own dims ----
#pragma unroll
    for (int q = 0; q < 5; ++q) {
      int sr = wave + 4 * q;
      if (sr < 18) {
        int dir = sr / 9;
        const float2* hv2 = (const float2*)hv + dir * 384;
        const float2* gv2 = (const float2*)ghrow + dir * 384;
        const float2* gf  = (const float2*)ghrow;
        float s1 = 0.f, s2 = 0.f, sm = 0.f;
#pragma unroll
        for (int pp = 0; pp < 6; ++pp) {
          int j = lane + 64 * pp;
          u32 v1 = wSHH[q][pp], v2 = wGHH[q][pp];
          float2 xh = hv2[j];
          float2 xg = gv2[j];
          s1 = fmaf(bflo(v1), xh.x, s1); s1 = fmaf(bfhi(v1), xh.y, s1);
          s2 = fmaf(bflo(v2), xg.x, s2); s2 = fmaf(bfhi(v2), xg.y, s2);
        }
#pragma unroll
        for (int pp = 0; pp < 12; ++pp) {
          int j = lane + 64 * pp;
          u32 v = wKV2[q][pp];
          float2 x = gf[j];
          sm = fmaf(bflo(v), x.x, sm); sm = fmaf(bfhi(v), x.y, sm);
        }
        s1 = wsum(s1); s2 = wsum(s2); sm = wsum(sm);
        if (lane == 0) {
          ghs_s[sr] = s1 + bSH[q];
          ghg_s[sr] = s2 + bGH[q];
          mcol[sr]  = sm + Mvb_l[sr];
        }
      }
    }
    if (t >= 1 && wave < 3) {
      const float2* gr2 = (const float2*)ghrow;
      float s = 0.f;
#pragma unroll
      for (int pp = 0; pp < 12; ++pp) {
        int j = lane + 64 * pp;
        float2 x = gr2[j];
        s = fmaf(wKV[2 * pp], x.x, s);
        s = fmaf(wKV[2 * pp + 1], x.y, s);
      }
      s = wsum(s);
      if (lane == 0)
        V_lds[t - 1][wave] = s + (wave == 0 ? vb0 : (wave == 1 ? vb1 : vb2));
    }
    bar_lds();
    // ---- publish ahead scores (tagged, target t+1) ----
    if (t >= 1 && wg <= t - 1 && t + 1 < U_ && tid < NREP)
      astore64(&g_mb_sc[((size_t)((t + 1) & 1) * NREP + tid) * U_ + wg],
               pk(red4b[0] + red4b[1] + red4b[2] + red4b[3], rb + (u32)(t + 1)));

    // ---- softmax + att-input via M (all local / tagged) ----
    if (t == 0) {
      if (tid < 18) gxs[tid] = A0_l[tid];
      if (tid < 3) att_s[tid] = a.att0[h0 + tid];
      bar_lds();
    } else {
      float sc;
      if (tid <= t - 2) {
        const u64* p = &g_mb_sc[((size_t)(t & 1) * NREP + myrep) * U_ + tid];
        u64 x = aload64(p);
        while (ptag(x) != tagT) x = aload64(p);
        sc = pf(x);
      } else if (tid == t - 1) {
        sc = red4[0] + red4[1] + red4[2] + red4[3];   // local score
      } else sc = (tid == t) ? 0.f : -3.0e38f;
      float m = wmax(sc);
      if (lane == 0) pmax[wave] = m;
      bar_lds();
      float mall = fmaxf(fmaxf(pmax[0], pmax[1]), fmaxf(pmax[2], pmax[3]));
      float e = 0.f, n0 = 0.f, n1 = 0.f, n2 = 0.f;
      if (tid <= t) {
        e = expf(sc - mall);
        if (tid < t) { n0 = e * V_lds[tid][0]; n1 = e * V_lds[tid][1]; n2 = e * V_lds[tid][2]; }
        else         { n0 = e * vb0; n1 = e * vb1; n2 = e * vb2; }
      }
      e_lds[tid] = e;
      float es = wsum(e); n0 = wsum(n0); n1 = wsum(n1); n2 = wsum(n2);
      if (lane == 0) { pnum[wave][0] = es; pnum[wave][1] = n0; pnum[wave][2] = n1; pnum[wave][3] = n2; }
      bar_lds();
      float den = pnum[0][0] + pnum[1][0] + pnum[2][0] + pnum[3][0];
      if (tid < 3) {
        float nn = pnum[0][tid + 1] + pnum[1][tid + 1] + pnum[2][tid + 1] + pnum[3][tid + 1];
        att_s[tid] = nn / den;
      }
#pragma unroll
      for (int q = 0; q < 5; ++q) {
        int sr = wave + 4 * q;
        if (sr < 18) {
          float dm = 0.f;
#pragma unroll
          for (int pp = 0; pp < 4; ++pp) {
            int j = lane + 64 * pp;
            dm += (j <= t - 2) ? e_lds[j] * M_l[sr][j] : 0.f;
          }
          dm = wsum(dm);
          if (lane == 0) {
            float mc = mcol[sr];
            gxs[sr] = (dm + e_lds[t - 1] * mc + e_lds[t] * Mvb_l[sr]) / den;
            M_l[sr][t - 1] = mc;
          }
        }
      }
      bar_lds();
    }

    // ---- P2: speaker GRU (fp32 hp carry) ----
    if (tid < 6) {
      int dir = tid / 3, d = tid - dir * 3, h = h0 + d;
      float xr = gxs[dir * 9 + d]     + sxu[dir * 9 + d];
      float xz = gxs[dir * 9 + 3 + d] + sxu[dir * 9 + 3 + d];
      float xn = gxs[dir * 9 + 6 + d] + sxu[dir * 9 + 6 + d];
      float hr = ghs_s[dir * 9 + d], hz = ghs_s[dir * 9 + 3 + d], hn = ghs_s[dir * 9 + 6 + d];
      float hp = (locc >= 0) ? hloc[sp][tid] : a.h0s[dir * E_ + h];
      float r = 1.f / (1.f + expf(-(xr + hr)));
      float z = 1.f / (1.f + expf(-(xz + hz)));
      float n = tanhf(xn + r * hn);
      float hnew = (1.f - z) * n + z * hp;
      float resid = dir ? a.dialogue[(size_t)t * E_ + h] : att_s[d];
      float so = hnew + resid;
      hloc[sp][tid] = hnew;
      pub12[tid] = hnew; pub12[6 + tid] = so;
      a.out[(size_t)U_ * E2_ + (size_t)t * E2_ + dir * E_ + h] = so;
    }
    bar_lds();
    // ---- publish so + h (tagged bf16 pairs) ----
    if (tid < 48) {
      int rep = tid & 15, slot = tid >> 4;
      u32 pay = packbf(pub12[6 + 2 * slot], pub12[7 + 2 * slot]);
      astore64(&g_mb_so[((size_t)rep * U_ + wg) * 4 + slot], (u64)pay | ((u64)tagT << 32));
    } else if (tid < 96) {
      int k = tid - 48, rep = k & 15, slot = k >> 4;
      u32 pay = packbf(pub12[2 * slot], pub12[1 + 2 * slot]);
      astore64(&g_mb_h[((((size_t)pocc_l[t] * NREP + rep) * U_ + wg) * 8 + sp) * 4 + slot],
               (u64)pay | ((u64)tagT << 32));
    }

    // ---- so gather (tag t) ----
    {
      const u64* p = &g_mb_so[((size_t)myrep * U_ + tid) * 4];
      u64 x0 = aload64(p), x1 = aload64(p + 1), x2 = aload64(p + 2);
      for (;;) {
        bool ok = (ptag(x0) == tagT) & (ptag(x1) == tagT) & (ptag(x2) == tagT);
        if (ok) break;
        if (ptag(x0) != tagT) x0 = aload64(p);
        if (ptag(x1) != tagT) x1 = aload64(p + 1);
        if (ptag(x2) != tagT) x2 = aload64(p + 2);
      }
      u32 w0 = (u32)x0, w1 = (u32)x1, w2 = (u32)x2;
      so_f[3 * tid]          = bflo(w0);
      so_f[3 * tid + 1]      = bfhi(w0);
      so_f[3 * tid + 2]      = bflo(w1);
      so_f[E_ + 3 * tid]     = bfhi(w1);
      so_f[E_ + 3 * tid + 1] = bflo(w2);
      so_f[E_ + 3 * tid + 2] = bfhi(w2);
    }
    bar_lds();
    // ---- P3: GSO matvec, global GRU, publish bg ----
#pragma unroll
    for (int q = 0; q < 5; ++q) {
      int sr = wave + 4 * q;
      if (sr < 18) {
        const float2* so2 = (const float2*)so_f;
        float s = 0.f;
#pragma unroll
        for (int pp = 0; pp < 12; ++pp) {
          int j = lane + 64 * pp;
          u32 v = wGSO[q][pp];
          float2 x = so2[j];
          s = fmaf(bflo(v), x.x, s); s = fmaf(bfhi(v), x.y, s);
        }
        s = wsum(s);
        if (lane == 0) gxs[sr] = s;
      }
    }
    bar_lds();
    if (tid < 6) {
      int dir = tid / 3, d = tid - dir * 3, h = h0 + d;
      float xr = gxs[dir * 9 + d]     + gxu[dir * 9 + d];
      float xz = gxs[dir * 9 + 3 + d] + gxu[dir * 9 + 3 + d];
      float xn = gxs[dir * 9 + 6 + d] + gxu[dir * 9 + 6 + d];
      float hr = ghg_s[dir * 9 + d], hz = ghg_s[dir * 9 + 3 + d], hn = ghg_s[dir * 9 + 6 + d];
      float hp = ghloc[tid];
      float r = 1.f / (1.f + expf(-(xr + hr)));
      float z = 1.f / (1.f + expf(-(xz + hz)));
      float n = tanhf(xn + r * hn);
      float hnew = (1.f - z) * n + z * hp;
      ghloc[tid] = hnew;
      pubbg[tid] = hnew;
      a.out[(size_t)t * E2_ + dir * E_ + h] = hnew;
    }
    bar_lds();
    if (tid < 48) {
      int rep = tid & 15, slot = tid >> 4;
      u32 pay = packbf(pubbg[2 * slot], pubbg[2 * slot + 1]);
      astore64(&g_mb_bg[((size_t)rep * U_ + wg) * 4 + slot], (u64)pay | ((u64)tagT << 32));
    }
  }
}

// ---------------- host ----------------
extern "C" void kernel_launch(void* const* d_in, const int* in_sizes, int n_in,
                              void* d_out, int out_size, void* d_ws, size_t ws_size,
                              hipStream_t stream)
{
  (void)in_sizes; (void)n_in; (void)out_size; (void)d_ws; (void)ws_size;
  const float* dialogue = (const float*)d_in[0];
  const int* speakers = (const int*)d_in[1];
  const float* Wq = (const float*)d_in[2];
  const float* bq = (const float*)d_in[3];
  const float* Wk = (const float*)d_in[4];
  const float* bk = (const float*)d_in[5];
  const float* Wv = (const float*)d_in[6];
  const float* bv = (const float*)d_in[7];
  const float* sWih_f = (const float*)d_in[8];
  const float* sWhh_f = (const float*)d_in[9];
  const float* sbih_f = (const float*)d_in[10];
  const float* sbhh_f = (const float*)d_in[11];
  const float* sWih_b = (const float*)d_in[12];
  const float* sWhh_b = (const float*)d_in[13];
  const float* sbih_b = (const float*)d_in[14];
  const float* sbhh_b = (const float*)d_in[15];
  const float* gWih_f = (const float*)d_in[16];
  const float* gWhh_f = (const float*)d_in[17];
  const float* gbih_f = (const float*)d_in[18];
  const float* gbhh_f = (const float*)d_in[19];
  const float* gWih_b = (const float*)d_in[20];
  const float* gWhh_b = (const float*)d_in[21];
  const float* gbih_b = (const float*)d_in[22];
  const float* gbhh_b = (const float*)d_in[23];
  const float* h0_global = (const float*)d_in[24];
  const float* h0_speaker = (const float*)d_in[25];
  const float* att0 = (const float*)d_in[26];

  init_kernel<<<dim3(12), dim3(256), 0, stream>>>(bk, Wv, bv);

  // g_Q = D @ Wq + bq
  gemm32<0, 0, 0, 0><<<dim3(12, 4), dim3(256), 0, stream>>>(
      dialogue, 768, Wq, 768, bq, 1.f, 768, 256, 768, 768);
  // g_WQg = g_Q @ Wk^T / norm
  gemm32<1, 1, 1, 0><<<dim3(24, 4), dim3(256), 0, stream>>>(
      nullptr, 768, Wk, 768, nullptr, 1.f / NORM_, 1536, 256, 1536, 768);
  // g_WKVT[e][k] = (Wk @ Wv)[k][e]
  gemm32<0, 0, 2, 1><<<dim3(12, 24), dim3(256), 0, stream>>>(
      Wk, 768, Wv, 768, nullptr, 1.f, 1536, 1536, 768, 768);

  SeqArgs args;
  args.dialogue = dialogue;
  args.sWih_f = sWih_f; args.sWih_b = sWih_b; args.sWhh_f = sWhh_f; args.sWhh_b = sWhh_b;
  args.sbih_f = sbih_f; args.sbih_b = sbih_b; args.sbhh_f = sbhh_f; args.sbhh_b = sbhh_b;
  args.gWih_f = gWih_f; args.gWih_b = gWih_b; args.gWhh_f = gWhh_f; args.gWhh_b = gWhh_b;
  args.gbih_f = gbih_f; args.gbih_b = gbih_b; args.gbhh_f = gbhh_f; args.gbhh_b = gbhh_b;
  args.att0 = att0; args.h0g = h0_global; args.h0s = h0_speaker;
  args.speakers = speakers;
  args.out = (float*)d_out;

  seq_kernel<<<dim3(256), dim3(256), 0, stream>>>(args);
}

// Round 8
// 5049.112 us; speedup vs baseline: 2.6943x; 2.3631x over previous
//
#include <hip/hip_runtime.h>
#include <hip/hip_bf16.h>

#define E_ 768
#define E2_ 1536
#define E3_ 2304
#define U_ 256
#define NORM_ 27.712812921102035f
#define NREP 16

typedef unsigned int u32;
typedef unsigned long long u64;

// ---------------- static device workspace ----------------
__device__ __align__(16) float g_Q[U_ * E_];       // D @ Wq + bq
__device__ __align__(16) float g_WQg[U_ * E2_];    // (Wk @ q_t)/norm, row t
__device__ __align__(16) float g_WKVT[E_ * E2_];   // (Wk@Wv)^T : [e][k]
__device__ __align__(16) float g_vb[E_];           // bk@Wv + bv
__device__ int g_run;                              // run counter (tag base)

// tagged mailboxes: u64 = {tag:32 | payload:32}; payload = 2 bf16 (or fp32 score)
// rows padded to 8 u64 = one full 64B line per (rep,row)
__device__ __align__(64) u64 g_mb_bg[NREP * U_ * 8];          // gh^t row dims (3 slots)
__device__ __align__(64) u64 g_mb_so[NREP * U_ * 8];          // so row dims (3 slots)
__device__ __align__(64) u64 g_mb_h [2 * NREP * U_ * 8 * 4];  // hstate, occ-parity slots
__device__ __align__(64) u64 g_mb_sc[2 * NREP * U_];          // scores, parity by target

__device__ __forceinline__ float bflo(u32 v){ return __uint_as_float(v << 16); }
__device__ __forceinline__ float bfhi(u32 v){ return __uint_as_float(v & 0xffff0000u); }

__device__ __forceinline__ u32 packbf(float lo, float hi){
  u32 a = __float_as_uint(lo), b = __float_as_uint(hi);
  a = (a + 0x7FFFu + ((a >> 16) & 1u)) >> 16;
  b = (b + 0x7FFFu + ((b >> 16) & 1u)) & 0xFFFF0000u;
  return (a & 0xFFFFu) | b;
}
__device__ __forceinline__ unsigned short bfr(float x){
  u32 a = __float_as_uint(x);
  return (unsigned short)((a + 0x7FFFu + ((a >> 16) & 1u)) >> 16);
}

__device__ __forceinline__ u64 aload64(const u64* p){
  return __hip_atomic_load(p, __ATOMIC_RELAXED, __HIP_MEMORY_SCOPE_AGENT);
}
__device__ __forceinline__ void astore64(u64* p, u64 v){
  __hip_atomic_store(p, v, __ATOMIC_RELAXED, __HIP_MEMORY_SCOPE_AGENT);
}
__device__ __forceinline__ u64 pk(float f, u32 tag){ return (u64)__float_as_uint(f) | ((u64)tag << 32); }
__device__ __forceinline__ float pf(u64 v){ return __uint_as_float((u32)v); }
__device__ __forceinline__ u32 ptag(u64 v){ return (u32)(v >> 32); }

// LDS-only barrier (no vmcnt drain; mailboxes are self-validating via tags)
__device__ __forceinline__ void bar_lds(){
  asm volatile("s_waitcnt lgkmcnt(0)\n\ts_barrier" ::: "memory");
}

__device__ __forceinline__ float wsum(float v){
#pragma unroll
  for (int o = 32; o > 0; o >>= 1) v += __shfl_xor(v, o, 64);
  return v;
}
__device__ __forceinline__ float wmax(float v){
#pragma unroll
  for (int o = 32; o > 0; o >>= 1) v = fmaxf(v, __shfl_xor(v, o, 64));
  return v;
}

// ---------------- init: run counter + vb ----------------
__global__ __launch_bounds__(256) void init_kernel(const float* bk, const float* Wv,
                                                   const float* bv)
{
  __shared__ float acc4[4][64];
  int tid = threadIdx.x;
  if (blockIdx.x == 0 && tid == 0) g_run = g_run + 1;
  int b = blockIdx.x;               // 0..11
  int o = b * 64 + (tid & 63);
  int w = tid >> 6;
  float s = 0.f;
  for (int i2 = w * 192; i2 < w * 192 + 192; ++i2)
    s = fmaf(bk[i2], Wv[(size_t)i2 * E_ + o], s);
  acc4[w][tid & 63] = s;
  __syncthreads();
  if (w == 0)
    g_vb[o] = acc4[0][tid & 63] + acc4[1][tid & 63] + acc4[2][tid & 63] + acc4[3][tid & 63] + bv[o];
}

// ---------------- fp32 tiled GEMM: C = scale*(A@B) + bias ----------------
template<int ASRC, int BNK, int DST, int TC>
__global__ __launch_bounds__(256) void gemm32(const float* __restrict__ Aext, int lda,
                                              const float* __restrict__ B, int ldb,
                                              const float* __restrict__ bias, float scale,
                                              int ldc, int M, int N, int K)
{
  const float* A = (ASRC == 1) ? g_Q : Aext;
  float* C = (DST == 0) ? g_Q : (DST == 1) ? g_WQg : g_WKVT;
  __shared__ float As[64][17];
  __shared__ float Bs[16][65];
  int tid = threadIdx.x;
  int tx = tid & 15, ty = tid >> 4;
  int m0 = blockIdx.y * 64, n0 = blockIdx.x * 64;
  float acc[4][4] = {{0.f}};
  for (int k0 = 0; k0 < K; k0 += 16) {
#pragma unroll
    for (int i = 0; i < 4; ++i) {
      int li = tid + 256 * i;
      int m = li >> 4, kk = li & 15;
      As[m][kk] = A[(size_t)(m0 + m) * lda + k0 + kk];
    }
#pragma unroll
    for (int i = 0; i < 4; ++i) {
      int li = tid + 256 * i;
      if (BNK) {
        int n = li >> 4, kk = li & 15;
        Bs[kk][n] = B[(size_t)(n0 + n) * ldb + k0 + kk];
      } else {
        int kk = li >> 6, n = li & 63;
        Bs[kk][n] = B[(size_t)(k0 + kk) * ldb + n0 + n];
      }
    }
    __syncthreads();
#pragma unroll
    for (int kk = 0; kk < 16; ++kk) {
      float av[4], bv4[4];
#pragma unroll
      for (int i = 0; i < 4; ++i) av[i] = As[ty * 4 + i][kk];
#pragma unroll
      for (int j = 0; j < 4; ++j) bv4[j] = Bs[kk][tx * 4 + j];
#pragma unroll
      for (int i = 0; i < 4; ++i)
#pragma unroll
        for (int j = 0; j < 4; ++j) acc[i][j] = fmaf(av[i], bv4[j], acc[i][j]);
    }
    __syncthreads();
  }
#pragma unroll
  for (int i = 0; i < 4; ++i)
#pragma unroll
    for (int j = 0; j < 4; ++j) {
      int m = m0 + ty * 4 + i, n = n0 + tx * 4 + j;
      float c = acc[i][j] * scale;
      if (bias) c += bias[n];
      if (TC) C[(size_t)n * ldc + m] = c;
      else    C[(size_t)m * ldc + n] = c;
    }
}

// ---------------- persistent sequential kernel ----------------
struct SeqArgs {
  const float *dialogue, *sWih_f, *sWih_b, *sWhh_f, *sWhh_b,
      *sbih_f, *sbih_b, *sbhh_f, *sbhh_b,
      *gWih_f, *gWih_b, *gWhh_f, *gWhh_b, *gbih_f, *gbih_b, *gbhh_f, *gbhh_b,
      *att0, *h0g, *h0s;
  const int* speakers;
  float* out;   // fp32: [U*2E buf][U*2E so]
};

__global__ __launch_bounds__(256, 1) void seq_kernel(SeqArgs a)
{
  const int tid = threadIdx.x, wg = blockIdx.x;
  const int wave = tid >> 6, lane = tid & 63;
  const int h0 = wg * 3;
  const int myrep = wg & (NREP - 1);

  __shared__ float wsa[18][768];      // setup: wSA rows fp32 -> then wsakv bf16 (read in-loop from LDS)
  __shared__ float wkv_lds[3][E2_];   // own 3 WKVT rows (fp32, read in-loop from LDS)
  __shared__ float M_l[18][U_];       // M[row][j] = wSA_row . v_j
  __shared__ float ghrow[E2_];        // gh^{t-1} (bf16-transported)
  __shared__ float bufc[E2_];         // own buf row (row wg)
  __shared__ float hv[E2_];           // hstate[sp] fwd/bwd (bf16-transported)
  __shared__ float so_f[E2_];         // gathered speaker output
  __shared__ float V_lds[U_][3];      // own att dims of v_j history
  __shared__ float e_lds[U_];
  __shared__ float ghs_s[18], ghg_s[18], sxu[18], gxu[18], gxs[18], mcol[18];
  __shared__ float Mvb_l[18], A0_l[18];
  __shared__ float red4[4], red4b[4], pmax[4], pnum[4][4], att_s[3];
  __shared__ float pub12[12], pubbg[6];
  __shared__ float hloc[8][6];        // fp32 carry: own hstate dims per speaker
  __shared__ float ghloc[6];          // fp32 carry: own gh dims
  __shared__ int spk_l[U_], locc_l[U_], pocc_l[U_];

  // ---- stage wSA rows (fp32) + own WKVT rows + speakers ----
  for (int idx = tid; idx < 18 * 768; idx += 256) {
    int r = idx / 768, e = idx - r * 768;
    int dir = r / 9, lr = r - dir * 9, g = lr / 3, d = lr - g * 3;
    int gr = g * E_ + h0 + d;
    const float* pa = (dir ? a.sWih_b : a.sWih_f) + (size_t)gr * E2_;
    wsa[r][e] = pa[e];
  }
  for (int idx = tid; idx < 3 * E2_; idx += 256) {
    int r = idx / E2_, k = idx - r * E2_;
    wkv_lds[r][k] = g_WKVT[(size_t)(h0 + r) * E2_ + k];
  }
  spk_l[tid] = a.speakers[tid] & 7;
  __syncthreads();
  {
    int mysp = spk_l[tid], lo = -1, cnt = 0;
    for (int s2 = 0; s2 <= tid; ++s2)
      if (spk_l[s2] == mysp) { cnt++; if (s2 < tid) lo = s2; }
    locc_l[tid] = lo;
    pocc_l[tid] = cnt & 1;
  }
  // ---- Mvb = wSA_row . vb ; A0 = wSA_row . att0 (fp32) ----
#pragma unroll
  for (int q = 0; q < 5; ++q) {
    int sr = wave + 4 * q;
    if (sr < 18) {
      float s0 = 0.f, s1 = 0.f;
#pragma unroll
      for (int pp = 0; pp < 12; ++pp) {
        int e = lane + 64 * pp;
        float w = wsa[sr][e];
        s0 = fmaf(w, g_vb[e], s0);
        s1 = fmaf(w, a.att0[e], s1);
      }
      s0 = wsum(s0); s1 = wsum(s1);
      if (lane == 0) { Mvb_l[sr] = s0; A0_l[sr] = s1; }
    }
  }
  __syncthreads();
  // ---- wsakv[r][k] = sum_e wSA_row[e] * WKVT[e][k]  (18x1536 -> bf16 in LDS) ----
  // two 9-row passes to keep the setup register watermark low (spill-free kernel)
  for (int half = 0; half < 2; ++half) {
    float acc[9][6];
#pragma unroll
    for (int r = 0; r < 9; ++r)
#pragma unroll
      for (int c = 0; c < 6; ++c) acc[r][c] = 0.f;
    for (int e = 0; e < 768; e += 2) {
      const float* B0 = g_WKVT + (size_t)e * E2_ + tid;
      const float* B1 = B0 + E2_;
      float b0[6], b1[6];
#pragma unroll
      for (int c = 0; c < 6; ++c) { b0[c] = B0[256 * c]; b1[c] = B1[256 * c]; }
#pragma unroll
      for (int r = 0; r < 9; ++r) {
        float2 w = ((const float2*)wsa[half * 9 + r])[e >> 1];
#pragma unroll
        for (int c = 0; c < 6; ++c)
          acc[r][c] = fmaf(w.x, b0[c], fmaf(w.y, b1[c], acc[r][c]));
      }
    }
    __syncthreads();
    unsigned short* wsp = (unsigned short*)wsa;
#pragma unroll
    for (int r = 0; r < 9; ++r)
#pragma unroll
      for (int c = 0; c < 6; ++c)
        wsp[(half * 9 + r) * 1536 + tid + 256 * c] = bfr(acc[r][c]);
    __syncthreads();
  }
  const u32* wsp32 = (const u32*)wsa;   // wsakv bf16-pairs, read from LDS in-loop

  // ---- weight slices kept in registers (fits without spills now) ----
  u32 wSU[5][6], wSHH[5][6], wGHH[5][6], wGSO[5][12], wGU[5][6];
  float bSH[5], bGH[5], bSI[5], bGI[5];
#pragma unroll
  for (int q = 0; q < 5; ++q) {
    int sr = wave + 4 * q;
    if (sr < 18) {
      int dir = sr / 9, lr = sr - dir * 9, g = lr / 3, d = lr - g * 3;
      int gr = g * E_ + h0 + d;
      const float* pa  = (dir ? a.sWih_b : a.sWih_f) + (size_t)gr * E2_;
      const float* ph  = (dir ? a.sWhh_b : a.sWhh_f) + (size_t)gr * E_;
      const float* pgs = (dir ? a.gWih_b : a.gWih_f) + (size_t)gr * E3_;
      const float* pgh = (dir ? a.gWhh_b : a.gWhh_f) + (size_t)gr * E_;
#pragma unroll
      for (int pp = 0; pp < 6; ++pp) {
        int j2 = 2 * (lane + 64 * pp);
        wSU[q][pp]  = packbf(pa[768 + j2], pa[768 + j2 + 1]);
        wSHH[q][pp] = packbf(ph[j2], ph[j2 + 1]);
        wGHH[q][pp] = packbf(pgh[j2], pgh[j2 + 1]);
        wGU[q][pp]  = packbf(pgs[1536 + j2], pgs[1536 + j2 + 1]);
      }
#pragma unroll
      for (int pp = 0; pp < 12; ++pp) {
        int j2 = 2 * (lane + 64 * pp);
        wGSO[q][pp] = packbf(pgs[j2], pgs[j2 + 1]);
      }
      bSH[q] = (dir ? a.sbhh_b : a.sbhh_f)[gr];
      bSI[q] = (dir ? a.sbih_b : a.sbih_f)[gr];
      bGH[q] = (dir ? a.gbhh_b : a.gbhh_f)[gr];
      bGI[q] = (dir ? a.gbih_b : a.gbih_f)[gr];
    }
  }
  const float vb0 = g_vb[h0], vb1 = g_vb[h0 + 1], vb2 = g_vb[h0 + 2];
  // fp32 carry init: own gh dims
  if (tid < 6) ghloc[tid] = a.h0g[(tid / 3) * E_ + h0 + (tid % 3)];
  __syncthreads();

  const u32 rb = ((u32)g_run) << 9;   // unique tag base per run

  for (int t = 0; t < U_; ++t) {
    const int sp = spk_l[t];
    const int locc = locc_l[t];
    const u32 tagT = rb + (u32)t;
    const float2* uv = (const float2*)(a.dialogue + (size_t)t * E_);

    // ---- pre-hop: u matvecs (overlap producer store flight) ----
#pragma unroll
    for (int q = 0; q < 5; ++q) {
      int sr = wave + 4 * q;
      if (sr < 18) {
        float s3 = 0.f, s4 = 0.f;
#pragma unroll
        for (int pp = 0; pp < 6; ++pp) {
          int j = lane + 64 * pp;
          u32 v3 = wSU[q][pp], v4 = wGU[q][pp];
          float2 xu = uv[j];
          s3 = fmaf(bflo(v3), xu.x, s3); s3 = fmaf(bfhi(v3), xu.y, s3);
          s4 = fmaf(bflo(v4), xu.x, s4); s4 = fmaf(bfhi(v4), xu.y, s4);
        }
        s3 = wsum(s3); s4 = wsum(s4);
        if (lane == 0) { sxu[sr] = s3 + bSI[q]; gxu[sr] = s4 + bGI[q]; }
      }
    }

    // ---- bg gather (tag t-1, 3 bf16-pair slots) + local score ----
    float slp = 0.f;
    if (t == 0) {
      for (int i = tid; i < E2_; i += 256) ghrow[i] = a.h0g[i];
    } else {
      const u64* p = &g_mb_bg[((size_t)myrep * U_ + tid) * 8];
      u64 x0 = aload64(p), x1 = aload64(p + 1), x2 = aload64(p + 2);
      const u32 exp = rb + (u32)(t - 1);
      for (;;) {
        bool ok = (ptag(x0) == exp) & (ptag(x1) == exp) & (ptag(x2) == exp);
        if (ok) break;
        if (ptag(x0) != exp) x0 = aload64(p);
        if (ptag(x1) != exp) x1 = aload64(p + 1);
        if (ptag(x2) != exp) x2 = aload64(p + 2);
      }
      u32 w0 = (u32)x0, w1 = (u32)x1, w2 = (u32)x2;
      float f0 = bflo(w0), f1 = bfhi(w0), f2 = bflo(w1);
      float f3 = bfhi(w1), f4 = bflo(w2), f5 = bfhi(w2);
      ghrow[3 * tid]          = f0;
      ghrow[3 * tid + 1]      = f1;
      ghrow[3 * tid + 2]      = f2;
      ghrow[E_ + 3 * tid]     = f3;
      ghrow[E_ + 3 * tid + 1] = f4;
      ghrow[E_ + 3 * tid + 2] = f5;
      if (wg == t - 1) {
        bufc[3 * tid]          = f0;
        bufc[3 * tid + 1]      = f1;
        bufc[3 * tid + 2]      = f2;
        bufc[E_ + 3 * tid]     = f3;
        bufc[E_ + 3 * tid + 1] = f4;
        bufc[E_ + 3 * tid + 2] = f5;
      }
      const float* wq = g_WQg + (size_t)t * E2_;
      slp = f0 * wq[3 * tid] + f1 * wq[3 * tid + 1] + f2 * wq[3 * tid + 2]
          + f3 * wq[E_ + 3 * tid] + f4 * wq[E_ + 3 * tid + 1] + f5 * wq[E_ + 3 * tid + 2];
    }
    // ---- h gather (tag locc, occurrence-parity slot) ----
    if (locc >= 0) {
      const int spar = pocc_l[t] ^ 1;
      const u64* p = &g_mb_h[((((size_t)spar * NREP + myrep) * U_ + tid) * 8 + sp) * 4];
      u64 x0 = aload64(p), x1 = aload64(p + 1), x2 = aload64(p + 2);
      const u32 exp = rb + (u32)locc;
      for (;;) {
        bool ok = (ptag(x0) == exp) & (ptag(x1) == exp) & (ptag(x2) == exp);
        if (ok) break;
        if (ptag(x0) != exp) x0 = aload64(p);
        if (ptag(x1) != exp) x1 = aload64(p + 1);
        if (ptag(x2) != exp) x2 = aload64(p + 2);
      }
      u32 w0 = (u32)x0, w1 = (u32)x1, w2 = (u32)x2;
      hv[3 * tid]          = bflo(w0);
      hv[3 * tid + 1]      = bfhi(w0);
      hv[3 * tid + 2]      = bflo(w1);
      hv[E_ + 3 * tid]     = bfhi(w1);
      hv[E_ + 3 * tid + 1] = bflo(w2);
      hv[E_ + 3 * tid + 2] = bfhi(w2);
    } else {
#pragma unroll
      for (int k = 0; k < 6; ++k) {
        int idx = (k / 3) * E_ + 3 * tid + (k % 3);
        hv[idx] = a.h0s[idx];
      }
    }
    slp = wsum(slp);
    if (lane == 0) red4[wave] = slp;
    bar_lds();

    // ---- ahead score for target t+1 (from bufc; includes row t-1) ----
    if (t >= 1 && wg <= t - 1 && t + 1 < U_) {
      const float2* bc2 = (const float2*)bufc;
      const float2* wq2 = (const float2*)(g_WQg + (size_t)(t + 1) * E2_);
      float sb = 0.f;
#pragma unroll
      for (int pp = 0; pp < 3; ++pp) {
        int j = tid + 256 * pp;
        float2 x = bc2[j];
        float2 w = wq2[j];
        sb = fmaf(x.x, w.x, sb); sb = fmaf(x.y, w.y, sb);
      }
      sb = wsum(sb);
      if (lane == 0) red4b[wave] = sb;
    }
    // ---- matvecs: SHH(hv), GHH(gh), wsakv(gh)->mcol (weights from LDS) ----
#pragma unroll
    for (int q = 0; q < 5; ++q) {
      int sr = wave + 4 * q;
      if (sr < 18) {
        int dir = sr / 9;
        const float2* hv2 = (const float2*)hv + dir * 384;
        const float2* gv2 = (const float2*)ghrow + dir * 384;
        const float2* gf  = (const float2*)ghrow;
        const u32* wrow = wsp32 + (size_t)sr * 768;
        float s1 = 0.f, s2 = 0.f, sm = 0.f;
#pragma unroll
        for (int pp = 0; pp < 6; ++pp) {
          int j = lane + 64 * pp;
          u32 v1 = wSHH[q][pp], v2 = wGHH[q][pp];
          float2 xh = hv2[j];
          float2 xg = gv2[j];
          s1 = fmaf(bflo(v1), xh.x, s1); s1 = fmaf(bfhi(v1), xh.y, s1);
          s2 = fmaf(bflo(v2), xg.x, s2); s2 = fmaf(bfhi(v2), xg.y, s2);
        }
#pragma unroll
        for (int pp = 0; pp < 12; ++pp) {
          int j = lane + 64 * pp;
          u32 v = wrow[j];
          float2 x = gf[j];
          sm = fmaf(bflo(v), x.x, sm); sm = fmaf(bfhi(v), x.y, sm);
        }
        s1 = wsum(s1); s2 = wsum(s2); sm = wsum(sm);
        if (lane == 0) {
          ghs_s[sr] = s1 + bSH[q];
          ghg_s[sr] = s2 + bGH[q];
          mcol[sr]  = sm + Mvb_l[sr];
        }
      }
    }
    if (t >= 1 && wave < 3) {
      const float2* gr2 = (const float2*)ghrow;
      const float2* kv2 = (const float2*)wkv_lds[wave];
      float s = 0.f;
#pragma unroll
      for (int pp = 0; pp < 12; ++pp) {
        int j = lane + 64 * pp;
        float2 x = gr2[j];
        float2 wv = kv2[j];
        s = fmaf(wv.x, x.x, s);
        s = fmaf(wv.y, x.y, s);
      }
      s = wsum(s);
      if (lane == 0)
        V_lds[t - 1][wave] = s + (wave == 0 ? vb0 : (wave == 1 ? vb1 : vb2));
    }
    bar_lds();
    // ---- publish ahead scores (tagged, target t+1) ----
    if (t >= 1 && wg <= t - 1 && t + 1 < U_ && tid < NREP)
      astore64(&g_mb_sc[((size_t)((t + 1) & 1) * NREP + tid) * U_ + wg],
               pk(red4b[0] + red4b[1] + red4b[2] + red4b[3], rb + (u32)(t + 1)));

    // ---- softmax + att-input via M (all local / tagged) ----
    if (t == 0) {
      if (tid < 18) gxs[tid] = A0_l[tid];
      if (tid < 3) att_s[tid] = a.att0[h0 + tid];
      bar_lds();
    } else {
      float sc;
      if (tid <= t - 2) {
        const u64* p = &g_mb_sc[((size_t)(t & 1) * NREP + myrep) * U_ + tid];
        u64 x = aload64(p);
        while (ptag(x) != tagT) x = aload64(p);
        sc = pf(x);
      } else if (tid == t - 1) {
        sc = red4[0] + red4[1] + red4[2] + red4[3];   // local score
      } else sc = (tid == t) ? 0.f : -3.0e38f;
      float m = wmax(sc);
      if (lane == 0) pmax[wave] = m;
      bar_lds();
      float mall = fmaxf(fmaxf(pmax[0], pmax[1]), fmaxf(pmax[2], pmax[3]));
      float e = 0.f, n0 = 0.f, n1 = 0.f, n2 = 0.f;
      if (tid <= t) {
        e = expf(sc - mall);
        if (tid < t) { n0 = e * V_lds[tid][0]; n1 = e * V_lds[tid][1]; n2 = e * V_lds[tid][2]; }
        else         { n0 = e * vb0; n1 = e * vb1; n2 = e * vb2; }
      }
      e_lds[tid] = e;
      float es = wsum(e); n0 = wsum(n0); n1 = wsum(n1); n2 = wsum(n2);
      if (lane == 0) { pnum[wave][0] = es; pnum[wave][1] = n0; pnum[wave][2] = n1; pnum[wave][3] = n2; }
      bar_lds();
      float den = pnum[0][0] + pnum[1][0] + pnum[2][0] + pnum[3][0];
      if (tid < 3) {
        float nn = pnum[0][tid + 1] + pnum[1][tid + 1] + pnum[2][tid + 1] + pnum[3][tid + 1];
        att_s[tid] = nn / den;
      }
#pragma unroll
      for (int q = 0; q < 5; ++q) {
        int sr = wave + 4 * q;
        if (sr < 18) {
          float dm = 0.f;
#pragma unroll
          for (int pp = 0; pp < 4; ++pp) {
            int j = lane + 64 * pp;
            dm += (j <= t - 2) ? e_lds[j] * M_l[sr][j] : 0.f;
          }
          dm = wsum(dm);
          if (lane == 0) {
            float mc = mcol[sr];
            gxs[sr] = (dm + e_lds[t - 1] * mc + e_lds[t] * Mvb_l[sr]) / den;
            M_l[sr][t - 1] = mc;
          }
        }
      }
      bar_lds();
    }

    // ---- P2: speaker GRU (fp32 hp carry) ----
    if (tid < 6) {
      int dir = tid / 3, d = tid - dir * 3, h = h0 + d;
      float xr = gxs[dir * 9 + d]     + sxu[dir * 9 + d];
      float xz = gxs[dir * 9 + 3 + d] + sxu[dir * 9 + 3 + d];
      float xn = gxs[dir * 9 + 6 + d] + sxu[dir * 9 + 6 + d];
      float hr = ghs_s[dir * 9 + d], hz = ghs_s[dir * 9 + 3 + d], hn = ghs_s[dir * 9 + 6 + d];
      float hp = (locc >= 0) ? hloc[sp][tid] : a.h0s[dir * E_ + h];
      float r = 1.f / (1.f + expf(-(xr + hr)));
      float z = 1.f / (1.f + expf(-(xz + hz)));
      float n = tanhf(xn + r * hn);
      float hnew = (1.f - z) * n + z * hp;
      float resid = dir ? a.dialogue[(size_t)t * E_ + h] : att_s[d];
      float so = hnew + resid;
      hloc[sp][tid] = hnew;
      pub12[tid] = hnew; pub12[6 + tid] = so;
      a.out[(size_t)U_ * E2_ + (size_t)t * E2_ + dir * E_ + h] = so;
    }
    bar_lds();
    // ---- publish so + h (tagged bf16 pairs) ----
    if (tid < 48) {
      int rep = tid & 15, slot = tid >> 4;
      u32 pay = packbf(pub12[6 + 2 * slot], pub12[7 + 2 * slot]);
      astore64(&g_mb_so[((size_t)rep * U_ + wg) * 8 + slot], (u64)pay | ((u64)tagT << 32));
    } else if (tid < 96) {
      int k = tid - 48, rep = k & 15, slot = k >> 4;
      u32 pay = packbf(pub12[2 * slot], pub12[1 + 2 * slot]);
      astore64(&g_mb_h[((((size_t)pocc_l[t] * NREP + rep) * U_ + wg) * 8 + sp) * 4 + slot],
               (u64)pay | ((u64)tagT << 32));
    }

    // ---- so gather (tag t) ----
    {
      const u64* p = &g_mb_so[((size_t)myrep * U_ + tid) * 8];
      u64 x0 = aload64(p), x1 = aload64(p + 1), x2 = aload64(p + 2);
      for (;;) {
        bool ok = (ptag(x0) == tagT) & (ptag(x1) == tagT) & (ptag(x2) == tagT);
        if (ok) break;
        if (ptag(x0) != tagT) x0 = aload64(p);
        if (ptag(x1) != tagT) x1 = aload64(p + 1);
        if (ptag(x2) != tagT) x2 = aload64(p + 2);
      }
      u32 w0 = (u32)x0, w1 = (u32)x1, w2 = (u32)x2;
      so_f[3 * tid]          = bflo(w0);
      so_f[3 * tid + 1]      = bfhi(w0);
      so_f[3 * tid + 2]      = bflo(w1);
      so_f[E_ + 3 * tid]     = bfhi(w1);
      so_f[E_ + 3 * tid + 1] = bflo(w2);
      so_f[E_ + 3 * tid + 2] = bfhi(w2);
    }
    bar_lds();
    // ---- P3: GSO matvec, global GRU, publish bg ----
#pragma unroll
    for (int q = 0; q < 5; ++q) {
      int sr = wave + 4 * q;
      if (sr < 18) {
        const float2* so2 = (const float2*)so_f;
        float s = 0.f;
#pragma unroll
        for (int pp = 0; pp < 12; ++pp) {
          int j = lane + 64 * pp;
          u32 v = wGSO[q][pp];
          float2 x = so2[j];
          s = fmaf(bflo(v), x.x, s); s = fmaf(bfhi(v), x.y, s);
        }
        s = wsum(s);
        if (lane == 0) gxs[sr] = s;
      }
    }
    bar_lds();
    if (tid < 6) {
      int dir = tid / 3, d = tid - dir * 3, h = h0 + d;
      float xr = gxs[dir * 9 + d]     + gxu[dir * 9 + d];
      float xz = gxs[dir * 9 + 3 + d] + gxu[dir * 9 + 3 + d];
      float xn = gxs[dir * 9 + 6 + d] + gxu[dir * 9 + 6 + d];
      float hr = ghg_s[dir * 9 + d], hz = ghg_s[dir * 9 + 3 + d], hn = ghg_s[dir * 9 + 6 + d];
      float hp = ghloc[tid];
      float r = 1.f / (1.f + expf(-(xr + hr)));
      float z = 1.f / (1.f + expf(-(xz + hz)));
      float n = tanhf(xn + r * hn);
      float hnew = (1.f - z) * n + z * hp;
      ghloc[tid] = hnew;
      pubbg[tid] = hnew;
      a.out[(size_t)t * E2_ + dir * E_ + h] = hnew;
    }
    bar_lds();
    if (tid < 48) {
      int rep = tid & 15, slot = tid >> 4;
      u32 pay = packbf(pubbg[2 * slot], pubbg[2 * slot + 1]);
      astore64(&g_mb_bg[((size_t)rep * U_ + wg) * 8 + slot], (u64)pay | ((u64)tagT << 32));
    }
  }
}

// ---------------- host ----------------
extern "C" void kernel_launch(void* const* d_in, const int* in_sizes, int n_in,
                              void* d_out, int out_size, void* d_ws, size_t ws_size,
                              hipStream_t stream)
{
  (void)in_sizes; (void)n_in; (void)out_size; (void)d_ws; (void)ws_size;
  const float* dialogue = (const float*)d_in[0];
  const int* speakers = (const int*)d_in[1];
  const float* Wq = (const float*)d_in[2];
  const float* bq = (const float*)d_in[3];
  const float* Wk = (const float*)d_in[4];
  const float* bk = (const float*)d_in[5];
  const float* Wv = (const float*)d_in[6];
  const float* bv = (const float*)d_in[7];
  const float* sWih_f = (const float*)d_in[8];
  const float* sWhh_f = (const float*)d_in[9];
  const float* sbih_f = (const float*)d_in[10];
  const float* sbhh_f = (const float*)d_in[11];
  const float* sWih_b = (const float*)d_in[12];
  const float* sWhh_b = (const float*)d_in[13];
  const float* sbih_b = (const float*)d_in[14];
  const float* sbhh_b = (const float*)d_in[15];
  const float* gWih_f = (const float*)d_in[16];
  const float* gWhh_f = (const float*)d_in[17];
  const float* gbih_f = (const float*)d_in[18];
  const float* gbhh_f = (const float*)d_in[19];
  const float* gWih_b = (const float*)d_in[20];
  const float* gWhh_b = (const float*)d_in[21];
  const float* gbih_b = (const float*)d_in[22];
  const float* gbhh_b = (const float*)d_in[23];
  const float* h0_global = (const float*)d_in[24];
  const float* h0_speaker = (const float*)d_in[25];
  const float* att0 = (const float*)d_in[26];

  init_kernel<<<dim3(12), dim3(256), 0, stream>>>(bk, Wv, bv);

  // g_Q = D @ Wq + bq
  gemm32<0, 0, 0, 0><<<dim3(12, 4), dim3(256), 0, stream>>>(
      dialogue, 768, Wq, 768, bq, 1.f, 768, 256, 768, 768);
  // g_WQg = g_Q @ Wk^T / norm
  gemm32<1, 1, 1, 0><<<dim3(24, 4), dim3(256), 0, stream>>>(
      nullptr, 768, Wk, 768, nullptr, 1.f / NORM_, 1536, 256, 1536, 768);
  // g_WKVT[e][k] = (Wk @ Wv)[k][e]
  gemm32<0, 0, 2, 1><<<dim3(12, 24), dim3(256), 0, stream>>>(
      Wk, 768, Wv, 768, nullptr, 1.f, 1536, 1536, 768, 768);

  SeqArgs args;
  args.dialogue = dialogue;
  args.sWih_f = sWih_f; args.sWih_b = sWih_b; args.sWhh_f = sWhh_f; args.sWhh_b = sWhh_b;
  args.sbih_f = sbih_f; args.sbih_b = sbih_b; args.sbhh_f = sbhh_f; args.sbhh_b = sbhh_b;
  args.gWih_f = gWih_f; args.gWih_b = gWih_b; args.gWhh_f = gWhh_f; args.gWhh_b = gWhh_b;
  args.gbih_f = gbih_f; args.gbih_b = gbih_b; args.gbhh_f = gbhh_f; args.gbhh_b = gbhh_b;
  args.att0 = att0; args.h0g = h0_global; args.h0s = h0_speaker;
  args.speakers = speakers;
  args.out = (float*)d_out;

  seq_kernel<<<dim3(256), dim3(256), 0, stream>>>(args);
}

// Round 9
// 4916.116 us; speedup vs baseline: 2.7672x; 1.0271x over previous
//
#include <hip/hip_runtime.h>
#include <hip/hip_bf16.h>

#define E_ 768
#define E2_ 1536
#define E3_ 2304
#define U_ 256
#define NORM_ 27.712812921102035f
#define NREP 16

typedef unsigned int u32;
typedef unsigned long long u64;

// ---------------- static device workspace ----------------
__device__ __align__(16) float g_Q[U_ * E_];       // D @ Wq + bq
__device__ __align__(16) float g_WQg[U_ * E2_];    // (Wk @ q_t)/norm, row t
__device__ __align__(16) float g_WKVT[E_ * E2_];   // (Wk@Wv)^T : [e][k]
__device__ __align__(16) float g_vb[E_];           // bk@Wv + bv
__device__ int g_run;                              // run counter (tag base)

// tagged mailboxes: u64 = {tag:32 | payload:32}; payload = 2 bf16 (or fp32 score)
__device__ __align__(64) u64 g_mb_bg[NREP * U_ * 8];          // gh^t row dims (3 slots)
__device__ __align__(64) u64 g_mb_so[NREP * U_ * 8];          // so row dims (3 slots)
__device__ __align__(64) u64 g_mb_h [2 * NREP * U_ * 8 * 4];  // hstate, occ-parity slots
__device__ __align__(64) u64 g_mb_sc[2 * NREP * U_];          // scores, parity by target

__device__ __forceinline__ float bflo(u32 v){ return __uint_as_float(v << 16); }
__device__ __forceinline__ float bfhi(u32 v){ return __uint_as_float(v & 0xffff0000u); }

__device__ __forceinline__ u32 packbf(float lo, float hi){
  u32 a = __float_as_uint(lo), b = __float_as_uint(hi);
  a = (a + 0x7FFFu + ((a >> 16) & 1u)) >> 16;
  b = (b + 0x7FFFu + ((b >> 16) & 1u)) & 0xFFFF0000u;
  return (a & 0xFFFFu) | b;
}
__device__ __forceinline__ unsigned short bfr(float x){
  u32 a = __float_as_uint(x);
  return (unsigned short)((a + 0x7FFFu + ((a >> 16) & 1u)) >> 16);
}

__device__ __forceinline__ u64 aload64(const u64* p){
  return __hip_atomic_load(p, __ATOMIC_RELAXED, __HIP_MEMORY_SCOPE_AGENT);
}
__device__ __forceinline__ void astore64(u64* p, u64 v){
  __hip_atomic_store(p, v, __ATOMIC_RELAXED, __HIP_MEMORY_SCOPE_AGENT);
}
__device__ __forceinline__ u64 pk(float f, u32 tag){ return (u64)__float_as_uint(f) | ((u64)tag << 32); }
__device__ __forceinline__ float pf(u64 v){ return __uint_as_float((u32)v); }
__device__ __forceinline__ u32 ptag(u64 v){ return (u32)(v >> 32); }

// LDS-only barrier (no vmcnt drain; mailboxes are self-validating via tags)
__device__ __forceinline__ void bar_lds(){
  asm volatile("s_waitcnt lgkmcnt(0)\n\ts_barrier" ::: "memory");
}

__device__ __forceinline__ float wsum(float v){
#pragma unroll
  for (int o = 32; o > 0; o >>= 1) v += __shfl_xor(v, o, 64);
  return v;
}
__device__ __forceinline__ float wmax(float v){
#pragma unroll
  for (int o = 32; o > 0; o >>= 1) v = fmaxf(v, __shfl_xor(v, o, 64));
  return v;
}

// ---------------- init: run counter + vb ----------------
__global__ __launch_bounds__(256) void init_kernel(const float* bk, const float* Wv,
                                                   const float* bv)
{
  __shared__ float acc4[4][64];
  int tid = threadIdx.x;
  if (blockIdx.x == 0 && tid == 0) g_run = g_run + 1;
  int b = blockIdx.x;               // 0..11
  int o = b * 64 + (tid & 63);
  int w = tid >> 6;
  float s = 0.f;
  for (int i2 = w * 192; i2 < w * 192 + 192; ++i2)
    s = fmaf(bk[i2], Wv[(size_t)i2 * E_ + o], s);
  acc4[w][tid & 63] = s;
  __syncthreads();
  if (w == 0)
    g_vb[o] = acc4[0][tid & 63] + acc4[1][tid & 63] + acc4[2][tid & 63] + acc4[3][tid & 63] + bv[o];
}

// ---------------- fp32 tiled GEMM: C = scale*(A@B) + bias ----------------
template<int ASRC, int BNK, int DST, int TC>
__global__ __launch_bounds__(256) void gemm32(const float* __restrict__ Aext, int lda,
                                              const float* __restrict__ B, int ldb,
                                              const float* __restrict__ bias, float scale,
                                              int ldc, int M, int N, int K)
{
  const float* A = (ASRC == 1) ? g_Q : Aext;
  float* C = (DST == 0) ? g_Q : (DST == 1) ? g_WQg : g_WKVT;
  __shared__ float As[64][17];
  __shared__ float Bs[16][65];
  int tid = threadIdx.x;
  int tx = tid & 15, ty = tid >> 4;
  int m0 = blockIdx.y * 64, n0 = blockIdx.x * 64;
  float acc[4][4] = {{0.f}};
  for (int k0 = 0; k0 < K; k0 += 16) {
#pragma unroll
    for (int i = 0; i < 4; ++i) {
      int li = tid + 256 * i;
      int m = li >> 4, kk = li & 15;
      As[m][kk] = A[(size_t)(m0 + m) * lda + k0 + kk];
    }
#pragma unroll
    for (int i = 0; i < 4; ++i) {
      int li = tid + 256 * i;
      if (BNK) {
        int n = li >> 4, kk = li & 15;
        Bs[kk][n] = B[(size_t)(n0 + n) * ldb + k0 + kk];
      } else {
        int kk = li >> 6, n = li & 63;
        Bs[kk][n] = B[(size_t)(k0 + kk) * ldb + n0 + n];
      }
    }
    __syncthreads();
#pragma unroll
    for (int kk = 0; kk < 16; ++kk) {
      float av[4], bv4[4];
#pragma unroll
      for (int i = 0; i < 4; ++i) av[i] = As[ty * 4 + i][kk];
#pragma unroll
      for (int j = 0; j < 4; ++j) bv4[j] = Bs[kk][tx * 4 + j];
#pragma unroll
      for (int i = 0; i < 4; ++i)
#pragma unroll
        for (int j = 0; j < 4; ++j) acc[i][j] = fmaf(av[i], bv4[j], acc[i][j]);
    }
    __syncthreads();
  }
#pragma unroll
  for (int i = 0; i < 4; ++i)
#pragma unroll
    for (int j = 0; j < 4; ++j) {
      int m = m0 + ty * 4 + i, n = n0 + tx * 4 + j;
      float c = acc[i][j] * scale;
      if (bias) c += bias[n];
      if (TC) C[(size_t)n * ldc + m] = c;
      else    C[(size_t)m * ldc + n] = c;
    }
}

// ---------------- persistent sequential kernel ----------------
struct SeqArgs {
  const float *dialogue, *sWih_f, *sWih_b, *sWhh_f, *sWhh_b,
      *sbih_f, *sbih_b, *sbhh_f, *sbhh_b,
      *gWih_f, *gWih_b, *gWhh_f, *gWhh_b, *gbih_f, *gbih_b, *gbhh_f, *gbhh_b,
      *att0, *h0g, *h0s;
  const int* speakers;
  float* out;   // fp32: [U*2E buf][U*2E so]
};

__global__ __launch_bounds__(256, 1) void seq_kernel(SeqArgs a)
{
  const int tid = threadIdx.x, wg = blockIdx.x;
  const int wave = tid >> 6, lane = tid & 63;
  const int h0 = wg * 3;
  const int myrep = wg & (NREP - 1);

  __shared__ float wsa[18][768];      // setup: wSA rows fp32 -> then wsakv bf16 (LDS)
  __shared__ float wkv_lds[3][E2_];   // own 3 WKVT rows (fp32)
  __shared__ float M_l[18][U_];       // M[row][j] = wSA_row . v_j
  __shared__ float ghrow[E2_];        // gh^{t-1}
  __shared__ float bufc[E2_];         // own buf row (row wg)
  __shared__ float hv[E2_];           // hstate[sp] fwd/bwd
  __shared__ float so_f[E2_];         // gathered speaker output
  __shared__ float wq_lds[E2_];       // prefetched WQg row t (for local score)
  __shared__ float V_lds[U_][3];      // own att dims of v_j history
  __shared__ float e_lds[U_];
  __shared__ float ghs_s[18], ghg_s[18], sxu[18], gxs[18], mcol[18];
  __shared__ float gxu2[2][18];       // global-GRU u-proj, parity double-buffer
  __shared__ float Mvb_l[18], A0_l[18], Mdotp[18];
  __shared__ float red4[4], red4b[4], pmax[4], pnum[4][4], att_s[3];
  __shared__ float mpart_s, denp_s, npart_s[3];
  __shared__ float pub12[12], pubbg[6];
  __shared__ float hloc[8][6];        // fp32 carry: own hstate dims per speaker
  __shared__ float ghloc[6];          // fp32 carry: own gh dims
  __shared__ int spk_l[U_], locc_l[U_], pocc_l[U_];

  // ---- stage wSA rows (fp32) + own WKVT rows + speakers ----
  for (int idx = tid; idx < 18 * 768; idx += 256) {
    int r = idx / 768, e = idx - r * 768;
    int dir = r / 9, lr = r - dir * 9, g = lr / 3, d = lr - g * 3;
    int gr = g * E_ + h0 + d;
    const float* pa = (dir ? a.sWih_b : a.sWih_f) + (size_t)gr * E2_;
    wsa[r][e] = pa[e];
  }
  for (int idx = tid; idx < 3 * E2_; idx += 256) {
    int r = idx / E2_, k = idx - r * E2_;
    wkv_lds[r][k] = g_WKVT[(size_t)(h0 + r) * E2_ + k];
  }
  spk_l[tid] = a.speakers[tid] & 7;
  __syncthreads();
  {
    int mysp = spk_l[tid], lo = -1, cnt = 0;
    for (int s2 = 0; s2 <= tid; ++s2)
      if (spk_l[s2] == mysp) { cnt++; if (s2 < tid) lo = s2; }
    locc_l[tid] = lo;
    pocc_l[tid] = cnt & 1;
  }
  // ---- Mvb = wSA_row . vb ; A0 = wSA_row . att0 (fp32) ----
#pragma unroll
  for (int q = 0; q < 5; ++q) {
    int sr = wave + 4 * q;
    if (sr < 18) {
      float s0 = 0.f, s1 = 0.f;
#pragma unroll
      for (int pp = 0; pp < 12; ++pp) {
        int e = lane + 64 * pp;
        float w = wsa[sr][e];
        s0 = fmaf(w, g_vb[e], s0);
        s1 = fmaf(w, a.att0[e], s1);
      }
      s0 = wsum(s0); s1 = wsum(s1);
      if (lane == 0) { Mvb_l[sr] = s0; A0_l[sr] = s1; }
    }
  }
  __syncthreads();
  // ---- wsakv[r][k] = sum_e wSA_row[e] * WKVT[e][k]  (18x1536 -> bf16 in LDS) ----
  for (int half = 0; half < 2; ++half) {
    float acc[9][6];
#pragma unroll
    for (int r = 0; r < 9; ++r)
#pragma unroll
      for (int c = 0; c < 6; ++c) acc[r][c] = 0.f;
    for (int e = 0; e < 768; e += 2) {
      const float* B0 = g_WKVT + (size_t)e * E2_ + tid;
      const float* B1 = B0 + E2_;
      float b0[6], b1[6];
#pragma unroll
      for (int c = 0; c < 6; ++c) { b0[c] = B0[256 * c]; b1[c] = B1[256 * c]; }
#pragma unroll
      for (int r = 0; r < 9; ++r) {
        float2 w = ((const float2*)wsa[half * 9 + r])[e >> 1];
#pragma unroll
        for (int c = 0; c < 6; ++c)
          acc[r][c] = fmaf(w.x, b0[c], fmaf(w.y, b1[c], acc[r][c]));
      }
    }
    __syncthreads();
    unsigned short* wsp = (unsigned short*)wsa;
#pragma unroll
    for (int r = 0; r < 9; ++r)
#pragma unroll
      for (int c = 0; c < 6; ++c)
        wsp[(half * 9 + r) * 1536 + tid + 256 * c] = bfr(acc[r][c]);
    __syncthreads();
  }
  const u32* wsp32 = (const u32*)wsa;   // wsakv bf16-pairs, read from LDS in-loop

  // ---- weight slices kept in registers ----
  u32 wSU[5][6], wSHH[5][6], wGHH[5][6], wGSO[5][12], wGU[5][6];
  float bSH[5], bGH[5], bSI[5], bGI[5];
#pragma unroll
  for (int q = 0; q < 5; ++q) {
    int sr = wave + 4 * q;
    if (sr < 18) {
      int dir = sr / 9, lr = sr - dir * 9, g = lr / 3, d = lr - g * 3;
      int gr = g * E_ + h0 + d;
      const float* pa  = (dir ? a.sWih_b : a.sWih_f) + (size_t)gr * E2_;
      const float* ph  = (dir ? a.sWhh_b : a.sWhh_f) + (size_t)gr * E_;
      const float* pgs = (dir ? a.gWih_b : a.gWih_f) + (size_t)gr * E3_;
      const float* pgh = (dir ? a.gWhh_b : a.gWhh_f) + (size_t)gr * E_;
#pragma unroll
      for (int pp = 0; pp < 6; ++pp) {
        int j2 = 2 * (lane + 64 * pp);
        wSU[q][pp]  = packbf(pa[768 + j2], pa[768 + j2 + 1]);
        wSHH[q][pp] = packbf(ph[j2], ph[j2 + 1]);
        wGHH[q][pp] = packbf(pgh[j2], pgh[j2 + 1]);
        wGU[q][pp]  = packbf(pgs[1536 + j2], pgs[1536 + j2 + 1]);
      }
#pragma unroll
      for (int pp = 0; pp < 12; ++pp) {
        int j2 = 2 * (lane + 64 * pp);
        wGSO[q][pp] = packbf(pgs[j2], pgs[j2 + 1]);
      }
      bSH[q] = (dir ? a.sbhh_b : a.sbhh_f)[gr];
      bSI[q] = (dir ? a.sbih_b : a.sbih_f)[gr];
      bGH[q] = (dir ? a.gbhh_b : a.gbhh_f)[gr];
      bGI[q] = (dir ? a.gbih_b : a.gbih_f)[gr];
    }
  }
  const float vb0 = g_vb[h0], vb1 = g_vb[h0 + 1], vb2 = g_vb[h0 + 2];
  if (tid < 6) ghloc[tid] = a.h0g[(tid / 3) * E_ + h0 + (tid % 3)];
  __syncthreads();

  // ---- region A (t=0): u-only matvecs ----
  {
    const float2* uv0 = (const float2*)a.dialogue;
#pragma unroll
    for (int q = 0; q < 5; ++q) {
      int sr = wave + 4 * q;
      if (sr < 18) {
        float s3 = 0.f, s4 = 0.f;
#pragma unroll
        for (int pp = 0; pp < 6; ++pp) {
          int j = lane + 64 * pp;
          u32 v3 = wSU[q][pp], v4 = wGU[q][pp];
          float2 xu = uv0[j];
          s3 = fmaf(bflo(v3), xu.x, s3); s3 = fmaf(bfhi(v3), xu.y, s3);
          s4 = fmaf(bflo(v4), xu.x, s4); s4 = fmaf(bfhi(v4), xu.y, s4);
        }
        s3 = wsum(s3); s4 = wsum(s4);
        if (lane == 0) { sxu[sr] = s3 + bSI[q]; gxu2[0][sr] = s4 + bGI[q]; }
      }
    }
  }

  const u32 rb = ((u32)g_run) << 9;   // unique tag base per run

  for (int t = 0; t < U_; ++t) {
    const int sp = spk_l[t];
    const int locc = locc_l[t];
    const u32 tagT = rb + (u32)t;

    // ---- bg gather (tag t-1) + local score (wq from LDS) + h gather ----
    float slp = 0.f;
    if (t == 0) {
      for (int i = tid; i < E2_; i += 256) ghrow[i] = a.h0g[i];
    } else {
      const u64* p = &g_mb_bg[((size_t)myrep * U_ + tid) * 8];
      u64 x0 = aload64(p), x1 = aload64(p + 1), x2 = aload64(p + 2);
      const u32 exp = rb + (u32)(t - 1);
      for (;;) {
        bool ok = (ptag(x0) == exp) & (ptag(x1) == exp) & (ptag(x2) == exp);
        if (ok) break;
        if (ptag(x0) != exp) x0 = aload64(p);
        if (ptag(x1) != exp) x1 = aload64(p + 1);
        if (ptag(x2) != exp) x2 = aload64(p + 2);
      }
      u32 w0 = (u32)x0, w1 = (u32)x1, w2 = (u32)x2;
      float f0 = bflo(w0), f1 = bfhi(w0), f2 = bflo(w1);
      float f3 = bfhi(w1), f4 = bflo(w2), f5 = bfhi(w2);
      ghrow[3 * tid]          = f0;
      ghrow[3 * tid + 1]      = f1;
      ghrow[3 * tid + 2]      = f2;
      ghrow[E_ + 3 * tid]     = f3;
      ghrow[E_ + 3 * tid + 1] = f4;
      ghrow[E_ + 3 * tid + 2] = f5;
      if (wg == t - 1) {
        bufc[3 * tid]          = f0;
        bufc[3 * tid + 1]      = f1;
        bufc[3 * tid + 2]      = f2;
        bufc[E_ + 3 * tid]     = f3;
        bufc[E_ + 3 * tid + 1] = f4;
        bufc[E_ + 3 * tid + 2] = f5;
      }
      slp = f0 * wq_lds[3 * tid] + f1 * wq_lds[3 * tid + 1] + f2 * wq_lds[3 * tid + 2]
          + f3 * wq_lds[E_ + 3 * tid] + f4 * wq_lds[E_ + 3 * tid + 1]
          + f5 * wq_lds[E_ + 3 * tid + 2];
    }
    if (locc >= 0) {
      const int spar = pocc_l[t] ^ 1;
      const u64* p = &g_mb_h[((((size_t)spar * NREP + myrep) * U_ + tid) * 8 + sp) * 4];
      u64 x0 = aload64(p), x1 = aload64(p + 1), x2 = aload64(p + 2);
      const u32 exp = rb + (u32)locc;
      for (;;) {
        bool ok = (ptag(x0) == exp) & (ptag(x1) == exp) & (ptag(x2) == exp);
        if (ok) break;
        if (ptag(x0) != exp) x0 = aload64(p);
        if (ptag(x1) != exp) x1 = aload64(p + 1);
        if (ptag(x2) != exp) x2 = aload64(p + 2);
      }
      u32 w0 = (u32)x0, w1 = (u32)x1, w2 = (u32)x2;
      hv[3 * tid]          = bflo(w0);
      hv[3 * tid + 1]      = bfhi(w0);
      hv[3 * tid + 2]      = bflo(w1);
      hv[E_ + 3 * tid]     = bfhi(w1);
      hv[E_ + 3 * tid + 1] = bflo(w2);
      hv[E_ + 3 * tid + 2] = bfhi(w2);
    } else {
#pragma unroll
      for (int k = 0; k < 6; ++k) {
        int idx = (k / 3) * E_ + 3 * tid + (k % 3);
        hv[idx] = a.h0s[idx];
      }
    }
    slp = wsum(slp);
    if (lane == 0) red4[wave] = slp;
    bar_lds();

    // ---- matvec phase: SHH(hv), GHH(gh), wsakv(gh)->mcol (+M column), V dims ----
#pragma unroll
    for (int q = 0; q < 5; ++q) {
      int sr = wave + 4 * q;
      if (sr < 18) {
        int dir = sr / 9;
        const float2* hv2 = (const float2*)hv + dir * 384;
        const float2* gv2 = (const float2*)ghrow + dir * 384;
        const float2* gf  = (const float2*)ghrow;
        const u32* wrow = wsp32 + (size_t)sr * 768;
        float s1 = 0.f, s2 = 0.f, sm = 0.f;
#pragma unroll
        for (int pp = 0; pp < 6; ++pp) {
          int j = lane + 64 * pp;
          u32 v1 = wSHH[q][pp], v2 = wGHH[q][pp];
          float2 xh = hv2[j];
          float2 xg = gv2[j];
          s1 = fmaf(bflo(v1), xh.x, s1); s1 = fmaf(bfhi(v1), xh.y, s1);
          s2 = fmaf(bflo(v2), xg.x, s2); s2 = fmaf(bfhi(v2), xg.y, s2);
        }
#pragma unroll
        for (int pp = 0; pp < 12; ++pp) {
          int j = lane + 64 * pp;
          u32 v = wrow[j];
          float2 x = gf[j];
          sm = fmaf(bflo(v), x.x, sm); sm = fmaf(bfhi(v), x.y, sm);
        }
        s1 = wsum(s1); s2 = wsum(s2); sm = wsum(sm);
        if (lane == 0) {
          ghs_s[sr] = s1 + bSH[q];
          ghg_s[sr] = s2 + bGH[q];
          float mc = sm + Mvb_l[sr];
          mcol[sr] = mc;
          if (t >= 1) M_l[sr][t - 1] = mc;
        }
      }
    }
    if (t >= 1 && wave < 3) {
      const float2* gr2 = (const float2*)ghrow;
      const float2* kv2 = (const float2*)wkv_lds[wave];
      float s = 0.f;
#pragma unroll
      for (int pp = 0; pp < 12; ++pp) {
        int j = lane + 64 * pp;
        float2 x = gr2[j];
        float2 wv = kv2[j];
        s = fmaf(wv.x, x.x, s);
        s = fmaf(wv.y, x.y, s);
      }
      s = wsum(s);
      if (lane == 0)
        V_lds[t - 1][wave] = s + (wave == 0 ? vb0 : (wave == 1 ? vb1 : vb2));
    }
    bar_lds();

    // ---- softmax MERGE (partials precomputed in shadow-B of t-1) ----
    if (t == 0) {
      if (tid < 18) gxs[tid] = A0_l[tid];
      if (tid < 3) att_s[tid] = a.att0[h0 + tid];
    } else {
      if (tid < 18) {
        float slpT = red4[0] + red4[1] + red4[2] + red4[3];
        float mp = mpart_s;
        float mall = fmaxf(fmaxf(mp, slpT), 0.f);
        float al = expf(mp - mall);
        float e1 = expf(slpT - mall);
        float e0 = expf(-mall);
        float den = al * denp_s + e1 + e0;
        gxs[tid] = (al * Mdotp[tid] + e1 * mcol[tid] + e0 * Mvb_l[tid]) / den;
        if (tid < 3) {
          float vbd = (tid == 0) ? vb0 : ((tid == 1) ? vb1 : vb2);
          att_s[tid] = (al * npart_s[tid] + e1 * V_lds[t - 1][tid] + e0 * vbd) / den;
        }
      }
    }
    bar_lds();

    // ---- P2: speaker GRU (fp32 hp carry) ----
    if (tid < 6) {
      int dir = tid / 3, d = tid - dir * 3, h = h0 + d;
      float xr = gxs[dir * 9 + d]     + sxu[dir * 9 + d];
      float xz = gxs[dir * 9 + 3 + d] + sxu[dir * 9 + 3 + d];
      float xn = gxs[dir * 9 + 6 + d] + sxu[dir * 9 + 6 + d];
      float hr = ghs_s[dir * 9 + d], hz = ghs_s[dir * 9 + 3 + d], hn = ghs_s[dir * 9 + 6 + d];
      float hp = (locc >= 0) ? hloc[sp][tid] : a.h0s[dir * E_ + h];
      float r = 1.f / (1.f + expf(-(xr + hr)));
      float z = 1.f / (1.f + expf(-(xz + hz)));
      float n = tanhf(xn + r * hn);
      float hnew = (1.f - z) * n + z * hp;
      float resid = dir ? a.dialogue[(size_t)t * E_ + h] : att_s[d];
      float so = hnew + resid;
      hloc[sp][tid] = hnew;
      pub12[tid] = hnew; pub12[6 + tid] = so;
      a.out[(size_t)U_ * E2_ + (size_t)t * E2_ + dir * E_ + h] = so;
    }
    bar_lds();
    // ---- publish so + h (tagged bf16 pairs) ----
    if (tid < 48) {
      int rep = tid & 15, slot = tid >> 4;
      u32 pay = packbf(pub12[6 + 2 * slot], pub12[7 + 2 * slot]);
      astore64(&g_mb_so[((size_t)rep * U_ + wg) * 8 + slot], (u64)pay | ((u64)tagT << 32));
    } else if (tid < 96) {
      int k = tid - 48, rep = k & 15, slot = k >> 4;
      u32 pay = packbf(pub12[2 * slot], pub12[1 + 2 * slot]);
      astore64(&g_mb_h[((((size_t)pocc_l[t] * NREP + rep) * U_ + wg) * 8 + sp) * 4 + slot],
               (u64)pay | ((u64)tagT << 32));
    }

    // ---- shadow-A (hides so-hop): next u matvecs, ahead score, WQg prefetch ----
    if (t + 1 < U_) {
      const float2* uvn = (const float2*)(a.dialogue + (size_t)(t + 1) * E_);
#pragma unroll
      for (int q = 0; q < 5; ++q) {
        int sr = wave + 4 * q;
        if (sr < 18) {
          float s3 = 0.f, s4 = 0.f;
#pragma unroll
          for (int pp = 0; pp < 6; ++pp) {
            int j = lane + 64 * pp;
            u32 v3 = wSU[q][pp], v4 = wGU[q][pp];
            float2 xu = uvn[j];
            s3 = fmaf(bflo(v3), xu.x, s3); s3 = fmaf(bfhi(v3), xu.y, s3);
            s4 = fmaf(bflo(v4), xu.x, s4); s4 = fmaf(bfhi(v4), xu.y, s4);
          }
          s3 = wsum(s3); s4 = wsum(s4);
          if (lane == 0) { sxu[sr] = s3 + bSI[q]; gxu2[(t + 1) & 1][sr] = s4 + bGI[q]; }
        }
      }
      if (wg <= t - 1) {
        const float2* bc2 = (const float2*)bufc;
        const float2* wq2 = (const float2*)(g_WQg + (size_t)(t + 1) * E2_);
        float sb = 0.f;
#pragma unroll
        for (int pp = 0; pp < 3; ++pp) {
          int j = tid + 256 * pp;
          float2 x = bc2[j];
          float2 w = wq2[j];
          sb = fmaf(x.x, w.x, sb); sb = fmaf(x.y, w.y, sb);
        }
        sb = wsum(sb);
        if (lane == 0) red4b[wave] = sb;
      }
      // prefetch WQg row t+1 into LDS for next gather's local score
      {
        const float* wn = g_WQg + (size_t)(t + 1) * E2_;
        for (int i = tid; i < E2_; i += 256) wq_lds[i] = wn[i];
      }
    }
    bar_lds();
    if (t >= 1 && wg <= t - 1 && t + 1 < U_ && tid < NREP)
      astore64(&g_mb_sc[((size_t)((t + 1) & 1) * NREP + tid) * U_ + wg],
               pk(red4b[0] + red4b[1] + red4b[2] + red4b[3], rb + (u32)(t + 1)));

    // ---- so gather (tag t) ----
    {
      const u64* p = &g_mb_so[((size_t)myrep * U_ + tid) * 8];
      u64 x0 = aload64(p), x1 = aload64(p + 1), x2 = aload64(p + 2);
      for (;;) {
        bool ok = (ptag(x0) == tagT) & (ptag(x1) == tagT) & (ptag(x2) == tagT);
        if (ok) break;
        if (ptag(x0) != tagT) x0 = aload64(p);
        if (ptag(x1) != tagT) x1 = aload64(p + 1);
        if (ptag(x2) != tagT) x2 = aload64(p + 2);
      }
      u32 w0 = (u32)x0, w1 = (u32)x1, w2 = (u32)x2;
      so_f[3 * tid]          = bflo(w0);
      so_f[3 * tid + 1]      = bfhi(w0);
      so_f[3 * tid + 2]      = bflo(w1);
      so_f[E_ + 3 * tid]     = bfhi(w1);
      so_f[E_ + 3 * tid + 1] = bflo(w2);
      so_f[E_ + 3 * tid + 2] = bfhi(w2);
    }
    bar_lds();
    // ---- P3: GSO matvec, global GRU, publish bg ----
#pragma unroll
    for (int q = 0; q < 5; ++q) {
      int sr = wave + 4 * q;
      if (sr < 18) {
        const float2* so2 = (const float2*)so_f;
        float s = 0.f;
#pragma unroll
        for (int pp = 0; pp < 12; ++pp) {
          int j = lane + 64 * pp;
          u32 v = wGSO[q][pp];
          float2 x = so2[j];
          s = fmaf(bflo(v), x.x, s); s = fmaf(bfhi(v), x.y, s);
        }
        s = wsum(s);
        if (lane == 0) gxs[sr] = s;
      }
    }
    bar_lds();
    if (tid < 6) {
      int dir = tid / 3, d = tid - dir * 3, h = h0 + d;
      float xr = gxs[dir * 9 + d]     + gxu2[t & 1][dir * 9 + d];
      float xz = gxs[dir * 9 + 3 + d] + gxu2[t & 1][dir * 9 + 3 + d];
      float xn = gxs[dir * 9 + 6 + d] + gxu2[t & 1][dir * 9 + 6 + d];
      float hr = ghg_s[dir * 9 + d], hz = ghg_s[dir * 9 + 3 + d], hn = ghg_s[dir * 9 + 6 + d];
      float hp = ghloc[tid];
      float r = 1.f / (1.f + expf(-(xr + hr)));
      float z = 1.f / (1.f + expf(-(xz + hz)));
      float n = tanhf(xn + r * hn);
      float hnew = (1.f - z) * n + z * hp;
      ghloc[tid] = hnew;
      pubbg[tid] = hnew;
      a.out[(size_t)t * E2_ + dir * E_ + h] = hnew;
    }
    bar_lds();
    if (tid < 48) {
      int rep = tid & 15, slot = tid >> 4;
      u32 pay = packbf(pubbg[2 * slot], pubbg[2 * slot + 1]);
      astore64(&g_mb_bg[((size_t)rep * U_ + wg) * 8 + slot], (u64)pay | ((u64)tagT << 32));
    }

    // ---- shadow-B (hides bg-hop): partial softmax for target t+1 ----
    if (t + 1 < U_) {
      float sc2;
      if (tid <= t - 1) {
        const u64* p = &g_mb_sc[((size_t)((t + 1) & 1) * NREP + myrep) * U_ + tid];
        u64 x = aload64(p);
        const u32 expn = rb + (u32)(t + 1);
        while (ptag(x) != expn) x = aload64(p);
        sc2 = pf(x);
      } else sc2 = -3.0e38f;
      float m = wmax(sc2);
      if (lane == 0) pmax[wave] = m;
      bar_lds();
      float mp = fmaxf(fmaxf(pmax[0], pmax[1]), fmaxf(pmax[2], pmax[3]));
      float e = 0.f, q0 = 0.f, q1 = 0.f, q2 = 0.f;
      if (tid <= t - 1) {
        e = expf(sc2 - mp);
        q0 = e * V_lds[tid][0]; q1 = e * V_lds[tid][1]; q2 = e * V_lds[tid][2];
      }
      e_lds[tid] = e;
      float es = wsum(e); q0 = wsum(q0); q1 = wsum(q1); q2 = wsum(q2);
      if (lane == 0) { pnum[wave][0] = es; pnum[wave][1] = q0; pnum[wave][2] = q1; pnum[wave][3] = q2; }
      bar_lds();
      if (tid == 0) {
        mpart_s = mp;
        denp_s = pnum[0][0] + pnum[1][0] + pnum[2][0] + pnum[3][0];
      }
      if (tid < 3)
        npart_s[tid] = pnum[0][tid + 1] + pnum[1][tid + 1] + pnum[2][tid + 1] + pnum[3][tid + 1];
#pragma unroll
      for (int q = 0; q < 5; ++q) {
        int sr = wave + 4 * q;
        if (sr < 18) {
          float dm = 0.f;
#pragma unroll
          for (int pp = 0; pp < 4; ++pp) {
            int j = lane + 64 * pp;
            dm += (j <= t - 1) ? e_lds[j] * M_l[sr][j] : 0.f;
          }
          dm = wsum(dm);
          if (lane == 0) Mdotp[sr] = dm;
        }
      }
    }
  }
}

// ---------------- host ----------------
extern "C" void kernel_launch(void* const* d_in, const int* in_sizes, int n_in,
                              void* d_out, int out_size, void* d_ws, size_t ws_size,
                              hipStream_t stream)
{
  (void)in_sizes; (void)n_in; (void)out_size; (void)d_ws; (void)ws_size;
  const float* dialogue = (const float*)d_in[0];
  const int* speakers = (const int*)d_in[1];
  const float* Wq = (const float*)d_in[2];
  const float* bq = (const float*)d_in[3];
  const float* Wk = (const float*)d_in[4];
  const float* bk = (const float*)d_in[5];
  const float* Wv = (const float*)d_in[6];
  const float* bv = (const float*)d_in[7];
  const float* sWih_f = (const float*)d_in[8];
  const float* sWhh_f = (const float*)d_in[9];
  const float* sbih_f = (const float*)d_in[10];
  const float* sbhh_f = (const float*)d_in[11];
  const float* sWih_b = (const float*)d_in[12];
  const float* sWhh_b = (const float*)d_in[13];
  const float* sbih_b = (const float*)d_in[14];
  const float* sbhh_b = (const float*)d_in[15];
  const float* gWih_f = (const float*)d_in[16];
  const float* gWhh_f = (const float*)d_in[17];
  const float* gbih_f = (const float*)d_in[18];
  const float* gbhh_f = (const float*)d_in[19];
  const float* gWih_b = (const float*)d_in[20];
  const float* gWhh_b = (const float*)d_in[21];
  const float* gbih_b = (const float*)d_in[22];
  const float* gbhh_b = (const float*)d_in[23];
  const float* h0_global = (const float*)d_in[24];
  const float* h0_speaker = (const float*)d_in[25];
  const float* att0 = (const float*)d_in[26];

  init_kernel<<<dim3(12), dim3(256), 0, stream>>>(bk, Wv, bv);

  // g_Q = D @ Wq + bq
  gemm32<0, 0, 0, 0><<<dim3(12, 4), dim3(256), 0, stream>>>(
      dialogue, 768, Wq, 768, bq, 1.f, 768, 256, 768, 768);
  // g_WQg = g_Q @ Wk^T / norm
  gemm32<1, 1, 1, 0><<<dim3(24, 4), dim3(256), 0, stream>>>(
      nullptr, 768, Wk, 768, nullptr, 1.f / NORM_, 1536, 256, 1536, 768);
  // g_WKVT[e][k] = (Wk @ Wv)[k][e]
  gemm32<0, 0, 2, 1><<<dim3(12, 24), dim3(256), 0, stream>>>(
      Wk, 768, Wv, 768, nullptr, 1.f, 1536, 1536, 768, 768);

  SeqArgs args;
  args.dialogue = dialogue;
  args.sWih_f = sWih_f; args.sWih_b = sWih_b; args.sWhh_f = sWhh_f; args.sWhh_b = sWhh_b;
  args.sbih_f = sbih_f; args.sbih_b = sbih_b; args.sbhh_f = sbhh_f; args.sbhh_b = sbhh_b;
  args.gWih_f = gWih_f; args.gWih_b = gWih_b; args.gWhh_f = gWhh_f; args.gWhh_b = gWhh_b;
  args.gbih_f = gbih_f; args.gbih_b = gbih_b; args.gbhh_f = gbhh_f; args.gbhh_b = gbhh_b;
  args.att0 = att0; args.h0g = h0_global; args.h0s = h0_speaker;
  args.speakers = speakers;
  args.out = (float*)d_out;

  seq_kernel<<<dim3(256), dim3(256), 0, stream>>>(args);
}